// Round 13
// baseline (518.220 us; speedup 1.0000x reference)
//
#include <hip/hip_runtime.h>
#include <hip/hip_bf16.h>
#include <stdint.h>

#define D_MODEL 1024
#define S_LEN 1024
#define BATCH 2
#define NHEADS 16
#define DK 64
#define DFF 4096

typedef __attribute__((ext_vector_type(8))) short short8;
typedef __attribute__((ext_vector_type(4))) float f32x4;

__device__ __forceinline__ unsigned short f2bf(float f) {
  union { float f; unsigned u; } v; v.f = f;
  unsigned r = v.u + 0x7FFFu + ((v.u >> 16) & 1u);
  return (unsigned short)(r >> 16);
}

__device__ __forceinline__ float bf2f(unsigned short s) {
  union { float f; unsigned u; } v; v.u = ((unsigned)s) << 16;
  return v.f;
}

__device__ __forceinline__ void gll16(const void* g, void* l) {
  __builtin_amdgcn_global_load_lds(
      (const __attribute__((address_space(1))) void*)g,
      (__attribute__((address_space(3))) void*)l, 16, 0, 0);
}

// ======== prep: all 4 weight transposes + mask prep + LN1 in ONE launch ======
__global__ __launch_bounds__(256)
void prep_kernel(const float* __restrict__ Wq, const float* __restrict__ Wo,
                 const float* __restrict__ W1, const float* __restrict__ W2,
                 const float* __restrict__ x, const float* __restrict__ ln1a,
                 const float* __restrict__ ln1b, const int* __restrict__ mask,
                 unsigned short* __restrict__ WqT, unsigned short* __restrict__ WoT,
                 unsigned short* __restrict__ W1T, unsigned short* __restrict__ W2T,
                 unsigned short* __restrict__ Mf, unsigned short* __restrict__ n1) {
  __shared__ unsigned short tile[32][33];
  __shared__ float red[10];
  const int id = blockIdx.x;
  const int tid = threadIdx.x;
  if (id < 10240) {
    // ---- weight transpose + f32->bf16 ----
    int wid = id;
    const float* W; unsigned short* Wt; int K, N, bx, by;
    if (wid < 1024)      { W = Wq; Wt = WqT; K = 1024; N = 1024; bx = wid & 31;  by = wid >> 5; }
    else if (wid < 2048) { wid -= 1024; W = Wo; Wt = WoT; K = 1024; N = 1024; bx = wid & 31;  by = wid >> 5; }
    else if (wid < 6144) { wid -= 2048; W = W1; Wt = W1T; K = 1024; N = 4096; bx = wid & 127; by = wid >> 7; }
    else                 { wid -= 6144; W = W2; Wt = W2T; K = 4096; N = 1024; bx = wid & 31;  by = wid >> 5; }
    const int k0 = by * 32, n0 = bx * 32;
    const int tx = tid & 31, ty = tid >> 5;
    #pragma unroll
    for (int i = 0; i < 4; i++) {
      int r = ty + i * 8;
      tile[r][tx] = f2bf(W[(int64_t)(k0 + r) * N + n0 + tx]);
    }
    __syncthreads();
    #pragma unroll
    for (int i = 0; i < 4; i++) {
      int r = ty + i * 8;
      Wt[(int64_t)(n0 + r) * K + k0 + tx] = tile[tx][r];
    }
  } else if (id < 11264) {
    // ---- mask -> bf16 fragment table ----
    const int gid = (id - 10240) * 256 + tid;   // [0, 262144)
    const int lo = gid & 15;
    const int ktb = (gid >> 4) & 31;
    const int q4 = (gid >> 9) & 255;
    const int b = gid >> 17;
    const int* mrow = mask + ((int64_t)b << 20) + (int64_t)q4 * 4096 + ktb * 32 + lo;
    union { unsigned short us[8]; short8 v; } o;
    #pragma unroll
    for (int r = 0; r < 4; r++) {
      o.us[r * 2]     = mrow[r * 1024]      ? 0x3F80 : 0;
      o.us[r * 2 + 1] = mrow[r * 1024 + 16] ? 0x3F80 : 0;
    }
    ((short8*)Mf)[gid] = o.v;
  } else {
    // ---- LayerNorm 1 (ddof=1) ----
    const int row = id - 11264;                 // [0, 2048)
    const float4 v = ((const float4*)(x + (int64_t)row * D_MODEL))[tid];
    float s = v.x + v.y + v.z + v.w;
    float ss = v.x * v.x + v.y * v.y + v.z * v.z + v.w * v.w;
    #pragma unroll
    for (int m = 32; m; m >>= 1) {
      s += __shfl_down(s, m);
      ss += __shfl_down(ss, m);
    }
    const int wave = tid >> 6;
    if ((tid & 63) == 0) { red[wave] = s; red[4 + wave] = ss; }
    __syncthreads();
    if (tid == 0) {
      float S = red[0] + red[1] + red[2] + red[3];
      float SS = red[4] + red[5] + red[6] + red[7];
      float mean = S * (1.f / 1024.f);
      float var = (SS - 1024.f * mean * mean) * (1.f / 1023.f);
      float inv = 1.f / (sqrtf(fmaxf(var, 0.f)) + 1e-6f);
      red[8] = mean; red[9] = inv;
    }
    __syncthreads();
    const float mean = red[8], inv = red[9];
    const float4 a = ((const float4*)ln1a)[tid];
    const float4 bb = ((const float4*)ln1b)[tid];
    union { unsigned short us[4]; uint2 u2; } pk;
    pk.us[0] = f2bf(a.x * (v.x - mean) * inv + bb.x);
    pk.us[1] = f2bf(a.y * (v.y - mean) * inv + bb.y);
    pk.us[2] = f2bf(a.z * (v.z - mean) * inv + bb.z);
    pk.us[3] = f2bf(a.w * (v.w - mean) * inv + bb.w);
    ((uint2*)(n1 + (int64_t)row * D_MODEL))[tid] = pk.u2;
  }
}

// ---------------- LayerNorm (standalone, for LN2) -----------------------------
__global__ __launch_bounds__(256)
void ln_kernel(const float* __restrict__ x,
               const float* __restrict__ alpha,
               const float* __restrict__ beta,
               unsigned short* __restrict__ out) {
  const int row = blockIdx.x;
  const int tid = threadIdx.x;
  const float4 v = ((const float4*)(x + (int64_t)row * D_MODEL))[tid];
  float s = v.x + v.y + v.z + v.w;
  float ss = v.x * v.x + v.y * v.y + v.z * v.z + v.w * v.w;
  #pragma unroll
  for (int m = 32; m; m >>= 1) {
    s += __shfl_down(s, m);
    ss += __shfl_down(ss, m);
  }
  __shared__ float red[10];
  const int wave = tid >> 6;
  if ((tid & 63) == 0) { red[wave] = s; red[4 + wave] = ss; }
  __syncthreads();
  if (tid == 0) {
    float S = red[0] + red[1] + red[2] + red[3];
    float SS = red[4] + red[5] + red[6] + red[7];
    float mean = S * (1.f / 1024.f);
    float var = (SS - 1024.f * mean * mean) * (1.f / 1023.f);
    float inv = 1.f / (sqrtf(fmaxf(var, 0.f)) + 1e-6f);
    red[8] = mean; red[9] = inv;
  }
  __syncthreads();
  const float mean = red[8], inv = red[9];
  const float4 a = ((const float4*)alpha)[tid];
  const float4 bb = ((const float4*)beta)[tid];
  union { unsigned short us[4]; uint2 u2; } pk;
  pk.us[0] = f2bf(a.x * (v.x - mean) * inv + bb.x);
  pk.us[1] = f2bf(a.y * (v.y - mean) * inv + bb.y);
  pk.us[2] = f2bf(a.z * (v.z - mean) * inv + bb.z);
  pk.us[3] = f2bf(a.w * (v.w - mean) * inv + bb.w);
  ((uint2*)(out + (int64_t)row * D_MODEL))[tid] = pk.u2;
}

// ---------------- per-head transpose: qkv[b][s][h*64+d] -> qkvT[b][h][d][s] --
__global__ __launch_bounds__(256)
void qkvt_kernel(const unsigned short* __restrict__ qkv,
                 unsigned short* __restrict__ qkvT) {
  __shared__ unsigned short tile[32][33];
  const int s0 = blockIdx.x * 32, d0 = blockIdx.y * 32, bh = blockIdx.z;
  const int b = bh >> 4, h = bh & 15;
  const int tx = threadIdx.x & 31, ty = threadIdx.x >> 5;
  #pragma unroll
  for (int i = 0; i < 4; i++) {
    int r = ty + i * 8;
    tile[r][tx] = qkv[(int64_t)(b * S_LEN + s0 + r) * D_MODEL + h * DK + d0 + tx];
  }
  __syncthreads();
  #pragma unroll
  for (int i = 0; i < 4; i++) {
    int r = ty + i * 8;
    qkvT[(int64_t)(bh * DK + d0 + r) * S_LEN + s0 + tx] = tile[tx][r];
  }
}

// ======== gemm_wk: 64x64 tile, 4 waves SPLIT K of each BK=128 step ===========
// Stage/sync identical to gemm_t. Wave w computes the FULL 64x64 tile over its
// 32-wide k-slice (chunk = w*4+hi): 8 ds_read per 16 MFMA (ratio 0.5 vs 1.0).
// One end-of-loop cross-wave reduce via LDS (all-static indexing, no dbuf).
template<int BIAS, int RELU, int RES, int OUTBF, int KSPLIT>
__global__ __launch_bounds__(256)
void gemm_wk(const unsigned short* __restrict__ A,
             const unsigned short* __restrict__ Bt,
             const float* __restrict__ bias,
             const float* __restrict__ res,
             void* __restrict__ outp,
             void* __restrict__ outp2,
             int M, int N, int K) {
  constexpr int BK = 128;
  __shared__ __align__(16) unsigned short S[2][8192];   // A = S[0], B = S[1]

  const int tid = threadIdx.x;
  const int lane = tid & 63;
  const int wave = tid >> 6;
  const int lo = lane & 15, hi = lane >> 4;

  int bid = blockIdx.x;
  int split = 0;
  if (KSPLIT == 2) { split = bid & 1; bid >>= 1; }
  const int cpx = (gridDim.x / KSPLIT) >> 3;
  const int sid = (bid & 7) * cpx + (bid >> 3);
  const int nbx = N >> 6;
  const int n0 = (sid % nbx) << 6;
  const int m0 = (sid / nbx) << 6;

  auto swz = [](int row, int c) -> int { return c ^ ((row & 7) << 1); };

  const int sr = lane >> 4;      // lane / 16  (NCH = 16)
  const int sc = lane & 15;

  f32x4 acc[4][4] = {};

  const int kbeg = split * (K / KSPLIT);
  const int kend = kbeg + K / KSPLIT;
  const int ch = wave * 4 + hi;  // this wave's k-chunk (32-wide slice)

  for (int k0 = kbeg; k0 < kend; k0 += BK) {
    #pragma unroll
    for (int r = 0; r < 4; r++) {
      const int row = r * 16 + wave * 4 + sr;
      gll16(A + (int64_t)(m0 + row) * K + k0 + swz(row, sc) * 8,
            &S[0][r * 2048 + wave * 512]);
      gll16(Bt + (int64_t)(n0 + row) * K + k0 + swz(row, sc) * 8,
            &S[1][r * 2048 + wave * 512]);
    }
    __syncthreads();
    short8 af[4], bf[4];
    #pragma unroll
    for (int t = 0; t < 4; t++) {
      const int row = t * 16 + lo;
      af[t] = *(const short8*)&S[0][row * BK + swz(row, ch) * 8];
      bf[t] = *(const short8*)&S[1][row * BK + swz(row, ch) * 8];
    }
    #pragma unroll
    for (int i = 0; i < 4; i++)
      #pragma unroll
      for (int j = 0; j < 4; j++)
        acc[i][j] = __builtin_amdgcn_mfma_f32_16x16x32_bf16(af[i], bf[j], acc[i][j], 0, 0, 0);
    __syncthreads();
  }

  // ---- cross-wave K reduction (waves hold partials of the SAME tile) ----
  float* red = (float*)&S[0][0];                    // 32 KB = 8192 f32
  if (wave >= 2) {
    #pragma unroll
    for (int i = 0; i < 4; i++)
      #pragma unroll
      for (int j = 0; j < 4; j++)
        *(f32x4*)&red[(wave - 2) * 4096 + (i * 4 + j) * 256 + lane * 4] = acc[i][j];
  }
  __syncthreads();
  if (wave < 2) {
    #pragma unroll
    for (int i = 0; i < 4; i++)
      #pragma unroll
      for (int j = 0; j < 4; j++)
        acc[i][j] += *(const f32x4*)&red[wave * 4096 + (i * 4 + j) * 256 + lane * 4];
  }
  __syncthreads();
  // swap halves: wave1 dumps its j<2, wave0 dumps its j>=2
  if (wave == 1) {
    #pragma unroll
    for (int i = 0; i < 4; i++)
      #pragma unroll
      for (int jj = 0; jj < 2; jj++)
        *(f32x4*)&red[(i * 2 + jj) * 256 + lane * 4] = acc[i][jj];
  } else if (wave == 0) {
    #pragma unroll
    for (int i = 0; i < 4; i++)
      #pragma unroll
      for (int jj = 0; jj < 2; jj++)
        *(f32x4*)&red[2048 + (i * 2 + jj) * 256 + lane * 4] = acc[i][2 + jj];
  }
  __syncthreads();

  if (wave < 2) {
    const int jb = wave * 2;             // wave0 -> cols j 0,1 ; wave1 -> j 2,3
    const int base = wave ? 2048 : 0;    // read the OTHER wave's dump
    float* Pout = (KSPLIT == 2) ? (split ? (float*)outp2 : (float*)outp) : nullptr;
    #pragma unroll
    for (int i = 0; i < 4; i++) {
      const int row = m0 + i * 16 + hi * 4;
      #pragma unroll
      for (int jj = 0; jj < 2; jj++) {
        const int j = jb + jj;
        f32x4 v4 = acc[i][j];
        v4 += *(const f32x4*)&red[base + (i * 2 + jj) * 256 + lane * 4];
        const int col = n0 + j * 16 + lo;
        #pragma unroll
        for (int r = 0; r < 4; r++) {
          float v = v4[r];
          if (KSPLIT == 2) {
            Pout[(int64_t)(row + r) * N + col] = v;
          } else {
            if (BIAS) v += bias[col];
            if (RELU) v = fmaxf(v, 0.f);
            if (RES)  v += res[(int64_t)(row + r) * N + col];
            if (OUTBF)
              ((unsigned short*)outp)[(int64_t)(row + r) * N + col] = f2bf(v);
            else
              ((float*)outp)[(int64_t)(row + r) * N + col] = v;
          }
        }
      }
    }
  }
}

// ---------------- GEMM (round-6 structure) — used by FFN1 --------------------
template<int BM, int BN, int BK, int BIAS, int RELU, int RES, int OUTBF, int KSPLIT>
__global__ __launch_bounds__(256)
void gemm_t(const unsigned short* __restrict__ A,
            const unsigned short* __restrict__ Bt,
            const float* __restrict__ bias,
            const float* __restrict__ res,
            void* __restrict__ outp,
            void* __restrict__ outp2,
            int M, int N, int K) {
  constexpr int NCH = BK / 8;
  constexpr int RPW = 512 / BK;
  constexpr int RPR = 2048 / BK;
  constexpr int RA = (BM * BK) / 2048;
  constexpr int RB = (BN * BK) / 2048;
  constexpr int MI = BM / 32;
  constexpr int NJ = BN / 32;
  constexpr int KK = BK / 32;

  __shared__ __align__(16) unsigned short As[BM * BK];
  __shared__ __align__(16) unsigned short Bs[BN * BK];

  const int tid = threadIdx.x;
  const int lane = tid & 63;
  const int wave = tid >> 6;
  const int lo = lane & 15, hi = lane >> 4;

  int bid = blockIdx.x;
  int split = 0;
  if (KSPLIT == 2) { split = bid & 1; bid >>= 1; }
  const int cpx = (gridDim.x / KSPLIT) >> 3;
  const int sid = (bid & 7) * cpx + (bid >> 3);
  const int nbx = N / BN;
  const int n0 = (sid % nbx) * BN;
  const int m0 = (sid / nbx) * BM;
  const int wr = (wave >> 1) * (BM / 2);
  const int wc = (wave & 1) * (BN / 2);

  auto swz = [](int row, int c) -> int {
    if (BK == 128) return c ^ ((row & 7) << 1);
    if (BK == 64)  return c ^ (row & 7);
    return c ^ ((row >> 1) & 3);   // BK == 32
  };

  const int sr = lane / NCH;
  const int sc = lane % NCH;

  f32x4 acc[MI][NJ] = {};

  const int kbeg = split * (K / KSPLIT);
  const int kend = kbeg + K / KSPLIT;
  for (int k0 = kbeg; k0 < kend; k0 += BK) {
    #pragma unroll
    for (int r = 0; r < RA; r++) {
      const int row = r * RPR + wave * RPW + sr;
      gll16(A + (int64_t)(m0 + row) * K + k0 + swz(row, sc) * 8,
            &As[r * 2048 + wave * 512]);
    }
    #pragma unroll
    for (int r = 0; r < RB; r++) {
      const int row = r * RPR + wave * RPW + sr;
      gll16(Bt + (int64_t)(n0 + row) * K + k0 + swz(row, sc) * 8,
            &Bs[r * 2048 + wave * 512]);
    }
    __syncthreads();
    #pragma unroll
    for (int kk = 0; kk < KK; kk++) {
      short8 af[MI], bfr[NJ];
      #pragma unroll
      for (int t = 0; t < MI; t++) {
        const int row = wr + t * 16 + lo;
        af[t] = *(const short8*)&As[row * BK + swz(row, kk * 4 + hi) * 8];
      }
      #pragma unroll
      for (int t = 0; t < NJ; t++) {
        const int row = wc + t * 16 + lo;
        bfr[t] = *(const short8*)&Bs[row * BK + swz(row, kk * 4 + hi) * 8];
      }
      #pragma unroll
      for (int i = 0; i < MI; i++)
        #pragma unroll
        for (int j = 0; j < NJ; j++)
          acc[i][j] = __builtin_amdgcn_mfma_f32_16x16x32_bf16(af[i], bfr[j], acc[i][j], 0, 0, 0);
    }
    __syncthreads();
  }

  float* Pout = (KSPLIT == 2) ? (split ? (float*)outp2 : (float*)outp) : nullptr;
  #pragma unroll
  for (int i = 0; i < MI; i++) {
    const int row = m0 + wr + i * 16 + hi * 4;
    #pragma unroll
    for (int j = 0; j < NJ; j++) {
      const int col = n0 + wc + j * 16 + lo;
      #pragma unroll
      for (int r = 0; r < 4; r++) {
        float v = acc[i][j][r];
        if (KSPLIT == 2) {
          Pout[(int64_t)(row + r) * N + col] = v;
        } else {
          if (BIAS) v += bias[col];
          if (RELU) v = fmaxf(v, 0.f);
          if (RES)  v += res[(int64_t)(row + r) * N + col];
          if (OUTBF)
            ((unsigned short*)outp)[(int64_t)(row + r) * N + col] = f2bf(v);
          else
            ((float*)outp)[(int64_t)(row + r) * N + col] = v;
        }
      }
    }
  }
}

// ---------------- FFN2 combine: out = x1(out) + B2 + P0 + P1 -----------------
__global__ __launch_bounds__(256)
void fcomb_kernel(const float* __restrict__ P0, const float* __restrict__ P1,
                  const float* __restrict__ bias, float* __restrict__ out) {
  const int i4 = blockIdx.x * 256 + threadIdx.x;     // 524288 float4
  const float4 a = ((const float4*)P0)[i4];
  const float4 b = ((const float4*)P1)[i4];
  const float4 bb = ((const float4*)bias)[i4 & 255];
  float4 c = ((const float4*)out)[i4];
  c.x += a.x + b.x + bb.x;
  c.y += a.y + b.y + bb.y;
  c.z += a.z + b.z + bb.z;
  c.w += a.w + b.w + bb.w;
  ((float4*)out)[i4] = c;
}

// -------- fused attention: LDS-staged K/V/M tiles, KV-split x2, XCD-local ----
__global__ __launch_bounds__(256)
void attn_kernel(const unsigned short* __restrict__ qkv,
                 const unsigned short* __restrict__ qkvT,
                 const unsigned short* __restrict__ Mf,
                 float* __restrict__ part,
                 float* __restrict__ psum) {
  __shared__ __align__(16) unsigned short Ks[64 * 64];
  __shared__ __align__(16) unsigned short Vs[64 * 64];
  __shared__ __align__(16) unsigned short Ms[512 * 8];
  __shared__ __align__(16) unsigned short Plds[4][16 * 40];
  const int tid = threadIdx.x;
  const int lane = tid & 63;
  const int wave = tid >> 6;
  const int lo = lane & 15, hi = lane >> 4;
  const int L = blockIdx.x;            // 1024 blocks
  const int xcd = L & 7, idx = L >> 3; // idx in [0,128)
  const int b = xcd >> 2;
  const int h = (xcd & 3) * 4 + (idx >> 5);
  const int split = (idx >> 4) & 1;
  const int qt = idx & 15;
  const int bh = b * 16 + h;
  const int q0 = qt * 64 + wave * 16;

  const unsigned short* qb =
      qkv + (int64_t)(b * S_LEN + q0 + lo) * D_MODEL + h * DK + hi * 8;
  const short8 qf0 = *(const short8*)qb;
  const short8 qf1 = *(const short8*)(qb + 32);

  f32x4 oacc[4] = {};
  float rsum[4] = {0.f, 0.f, 0.f, 0.f};
  unsigned short* Pw = Plds[wave];
  const int kbeg = split * 512;
  const int q4w = wave * 4 + hi;
  const int xr = lo & 7;

  for (int kti = 0; kti < 8; kti++) {
    const int kt = kbeg + kti * 64;
    #pragma unroll
    for (int r = 0; r < 2; r++) {
      const int c = r * 256 + tid;
      const int row = c >> 3;
      const int chg = (c & 7) ^ (row & 7);
      gll16(qkv + (int64_t)(b * S_LEN + kt + row) * D_MODEL + h * DK + chg * 8,
            &Ks[(r * 256 + wave * 64) * 8]);
      gll16(qkvT + (int64_t)(bh * DK + row) * S_LEN + kt + chg * 8,
            &Vs[(r * 256 + wave * 64) * 8]);
      const int q4l = c >> 5;
      const int u2 = (c >> 4) & 1;
      const int log = (c & 15) ^ q4l;
      gll16(Mf + ((int64_t)((b * 256 + qt * 16 + q4l) * 32 + (kt >> 5) + u2) * 16 + log) * 8,
            &Ms[(r * 256 + wave * 64) * 8]);
    }
    __syncthreads();
    #pragma unroll
    for (int u = 0; u < 2; u++) {
      const short8 kf00 = *(const short8*)&Ks[((u * 32 + lo) * 8 + (hi ^ xr)) * 8];
      const short8 kf01 = *(const short8*)&Ks[((u * 32 + lo) * 8 + ((4 + hi) ^ xr)) * 8];
      const short8 kf10 = *(const short8*)&Ks[((u * 32 + 16 + lo) * 8 + (hi ^ xr)) * 8];
      const short8 kf11 = *(const short8*)&Ks[((u * 32 + 16 + lo) * 8 + ((4 + hi) ^ xr)) * 8];
      const short8 mf = *(const short8*)&Ms[(q4w * 32 + u * 16 + (lo ^ q4w)) * 8];
      f32x4 s0 = {}, s1 = {};
      s0 = __builtin_amdgcn_mfma_f32_16x16x32_bf16(qf0, kf00, s0, 0, 0, 0);
      s0 = __builtin_amdgcn_mfma_f32_16x16x32_bf16(qf1, kf01, s0, 0, 0, 0);
      s1 = __builtin_amdgcn_mfma_f32_16x16x32_bf16(qf0, kf10, s1, 0, 0, 0);
      s1 = __builtin_amdgcn_mfma_f32_16x16x32_bf16(qf1, kf11, s1, 0, 0, 0);
      #pragma unroll
      for (int r = 0; r < 4; r++) {
        const float m0_ = bf2f((unsigned short)mf[r * 2]);
        const float m1_ = bf2f((unsigned short)mf[r * 2 + 1]);
        const float e0_ = __expf(s0[r] * 0.125f);
        const float e1_ = __expf(s1[r] * 0.125f);
        const float p0_ = fmaf(m0_, e0_ - 1.f, 1.f);
        const float p1_ = fmaf(m1_, e1_ - 1.f, 1.f);
        rsum[r] += p0_ + p1_;
        Pw[(hi * 4 + r) * 40 + lo]      = f2bf(p0_);
        Pw[(hi * 4 + r) * 40 + 16 + lo] = f2bf(p1_);
      }
      const short8 pf = *(const short8*)&Pw[lo * 40 + hi * 8];
      #pragma unroll
      for (int t = 0; t < 4; t++) {
        const short8 vf = *(const short8*)&Vs[((t * 16 + lo) * 8 + ((u * 4 + hi) ^ xr)) * 8];
        oacc[t] = __builtin_amdgcn_mfma_f32_16x16x32_bf16(pf, vf, oacc[t], 0, 0, 0);
      }
    }
    __syncthreads();
  }

  #pragma unroll
  for (int m = 1; m < 16; m <<= 1)
    #pragma unroll
    for (int r = 0; r < 4; r++) rsum[r] += __shfl_xor(rsum[r], m);

  const int64_t prow = (int64_t)(split * 32 + bh) * 1024;
  #pragma unroll
  for (int t = 0; t < 4; t++)
    #pragma unroll
    for (int r = 0; r < 4; r++)
      part[(prow + q0 + hi * 4 + r) * 64 + t * 16 + lo] = oacc[t][r];
  if (lo == 0)
    #pragma unroll
    for (int r = 0; r < 4; r++)
      psum[prow + q0 + hi * 4 + r] = rsum[r];
}

// ---------------- combine KV-split partials -> ctx (bf16) --------------------
__global__ __launch_bounds__(256)
void acomb_kernel(const float* __restrict__ part,
                  const float* __restrict__ psum,
                  unsigned short* __restrict__ ctx) {
  const int idx4 = blockIdx.x * 256 + threadIdx.x;   // 524288
  const int d4 = idx4 & 15;
  const int q = (idx4 >> 4) & 1023;
  const int bh = idx4 >> 14;
  const int b = bh >> 4, h = bh & 15;
  const float4* p4 = (const float4*)part;
  const float4 a0 = p4[(int64_t)(bh * 1024 + q) * 16 + d4];
  const float4 a1 = p4[524288 + (int64_t)(bh * 1024 + q) * 16 + d4];
  const float rs = psum[bh * 1024 + q] + psum[32768 + bh * 1024 + q];
  const float inv = 1.f / rs;
  union { unsigned short us[4]; uint2 u2; } pk;
  pk.us[0] = f2bf((a0.x + a1.x) * inv);
  pk.us[1] = f2bf((a0.y + a1.y) * inv);
  pk.us[2] = f2bf((a0.z + a1.z) * inv);
  pk.us[3] = f2bf((a0.w + a1.w) * inv);
  *(uint2*)(ctx + (int64_t)(b * S_LEN + q) * D_MODEL + h * DK + d4 * 4) = pk.u2;
}

// -----------------------------------------------------------------------------
extern "C" void kernel_launch(void* const* d_in, const int* in_sizes, int n_in,
                              void* d_out, int out_size, void* d_ws, size_t ws_size,
                              hipStream_t stream) {
  (void)in_sizes; (void)n_in; (void)out_size; (void)ws_size;
  const float* x    = (const float*)d_in[0];
  const int*   mask = (const int*)d_in[1];
  const float* Wq   = (const float*)d_in[2];
  const float* Wo   = (const float*)d_in[3];
  const float* W1   = (const float*)d_in[4];
  const float* B1   = (const float*)d_in[5];
  const float* W2   = (const float*)d_in[6];
  const float* B2   = (const float*)d_in[7];
  const float* ln1a = (const float*)d_in[8];
  const float* ln1b = (const float*)d_in[9];
  const float* ln2a = (const float*)d_in[10];
  const float* ln2b = (const float*)d_in[11];
  float* out = (float*)d_out;

  char* ws = (char*)d_ws;
  unsigned short* WqT  = (unsigned short*)(ws);                     // [0,2) MB
  unsigned short* WoT  = (unsigned short*)(ws + (2ull  << 20));     // [2,4)
  unsigned short* W1T  = (unsigned short*)(ws + (4ull  << 20));     // [4,12)
  float*          Pf0  = (float*)(ws + (4ull  << 20));              // FFN2 partial 0 (W1T dead)
  unsigned short* W2T  = (unsigned short*)(ws + (12ull << 20));     // [12,20)
  unsigned short* n1   = (unsigned short*)(ws + (20ull << 20));     // [20,24)
  float*          psum = (float*)(ws + (20ull << 20));              // reuses n1 (attn+)
  unsigned short* qkv  = (unsigned short*)(ws + (24ull << 20));     // [24,28)
  unsigned short* qkvT = (unsigned short*)(ws + (28ull << 20));     // [28,32)
  unsigned short* Mf   = (unsigned short*)(ws + (32ull << 20));     // [32,36)
  unsigned short* ctx  = (unsigned short*)(ws + (32ull << 20));     // [32,36) (Mf dead)
  float*          Pf1  = (float*)(ws + (32ull << 20));              // FFN2 partial 1 (ctx+n2 dead)
  unsigned short* n2   = (unsigned short*)(ws + (36ull << 20));     // [36,40)
  float*          part = (float*)(ws + (40ull << 20));              // [40,56) attn partials
  unsigned short* h1   = (unsigned short*)(ws + (40ull << 20));     // [40,56) FFN1 out (part dead)
  float* x1 = out;  // residual-1 result lives in d_out (fully rewritten later)

  dim3 blk(256);
  // prep: 10240 wt + 1024 mprep + 2048 ln1
  prep_kernel<<<13312, blk, 0, stream>>>(Wq, Wo, W1, W2, x, ln1a, ln1b, mask,
                                         WqT, WoT, W1T, W2T, Mf, n1);
  gemm_wk<0,0,0,1,1><<<512, blk, 0, stream>>>(n1, WqT, nullptr, nullptr, qkv, nullptr, 2048, 1024, 1024);
  qkvt_kernel<<<dim3(32, 2, 32), blk, 0, stream>>>(qkv, qkvT);
  attn_kernel<<<1024, blk, 0, stream>>>(qkv, qkvT, Mf, part, psum);
  acomb_kernel<<<2048, blk, 0, stream>>>(part, psum, ctx);
  gemm_wk<0,0,1,0,1><<<512, blk, 0, stream>>>(ctx, WoT, nullptr, x, x1, nullptr, 2048, 1024, 1024);
  ln_kernel<<<2048, blk, 0, stream>>>(x1, ln2a, ln2b, n2);
  // FFN1: 64x128 tile (r12 config, proven neutral-or-equal)
  gemm_t<64,128,64, 1,1,0,1,1><<<1024, blk, 0, stream>>>(n2, W1T, B1, nullptr, h1, nullptr, 2048, 4096, 1024);
  // FFN2: block K-split x2 + wave K-split
  gemm_wk<0,0,0,0,2><<<1024, blk, 0, stream>>>(h1, W2T, nullptr, nullptr, Pf0, Pf1, 2048, 1024, 4096);
  fcomb_kernel<<<2048, blk, 0, stream>>>(Pf0, Pf1, B2, out);
}

// Round 14
// 136.210 us; speedup vs baseline: 3.8046x; 3.8046x over previous
//
#include <hip/hip_runtime.h>
#include <hip/hip_bf16.h>
#include <stdint.h>

#define D_MODEL 1024
#define S_LEN 1024
#define BATCH 2
#define NHEADS 16
#define DK 64
#define DFF 4096

typedef __attribute__((ext_vector_type(8))) short short8;
typedef __attribute__((ext_vector_type(4))) float f32x4;

__device__ __forceinline__ unsigned short f2bf(float f) {
  union { float f; unsigned u; } v; v.f = f;
  unsigned r = v.u + 0x7FFFu + ((v.u >> 16) & 1u);
  return (unsigned short)(r >> 16);
}

__device__ __forceinline__ float bf2f(unsigned short s) {
  union { float f; unsigned u; } v; v.u = ((unsigned)s) << 16;
  return v.f;
}

__device__ __forceinline__ void gll16(const void* g, void* l) {
  __builtin_amdgcn_global_load_lds(
      (const __attribute__((address_space(1))) void*)g,
      (__attribute__((address_space(3))) void*)l, 16, 0, 0);
}

// ======== prep: all 4 weight transposes + mask prep + LN1 in ONE launch ======
__global__ __launch_bounds__(256)
void prep_kernel(const float* __restrict__ Wq, const float* __restrict__ Wo,
                 const float* __restrict__ W1, const float* __restrict__ W2,
                 const float* __restrict__ x, const float* __restrict__ ln1a,
                 const float* __restrict__ ln1b, const int* __restrict__ mask,
                 unsigned short* __restrict__ WqT, unsigned short* __restrict__ WoT,
                 unsigned short* __restrict__ W1T, unsigned short* __restrict__ W2T,
                 unsigned short* __restrict__ Mf, unsigned short* __restrict__ n1) {
  __shared__ unsigned short tile[32][33];
  __shared__ float red[10];
  const int id = blockIdx.x;
  const int tid = threadIdx.x;
  if (id < 10240) {
    int wid = id;
    const float* W; unsigned short* Wt; int K, N, bx, by;
    if (wid < 1024)      { W = Wq; Wt = WqT; K = 1024; N = 1024; bx = wid & 31;  by = wid >> 5; }
    else if (wid < 2048) { wid -= 1024; W = Wo; Wt = WoT; K = 1024; N = 1024; bx = wid & 31;  by = wid >> 5; }
    else if (wid < 6144) { wid -= 2048; W = W1; Wt = W1T; K = 1024; N = 4096; bx = wid & 127; by = wid >> 7; }
    else                 { wid -= 6144; W = W2; Wt = W2T; K = 4096; N = 1024; bx = wid & 31;  by = wid >> 5; }
    const int k0 = by * 32, n0 = bx * 32;
    const int tx = tid & 31, ty = tid >> 5;
    #pragma unroll
    for (int i = 0; i < 4; i++) {
      int r = ty + i * 8;
      tile[r][tx] = f2bf(W[(int64_t)(k0 + r) * N + n0 + tx]);
    }
    __syncthreads();
    #pragma unroll
    for (int i = 0; i < 4; i++) {
      int r = ty + i * 8;
      Wt[(int64_t)(n0 + r) * K + k0 + tx] = tile[tx][r];
    }
  } else if (id < 11264) {
    const int gid = (id - 10240) * 256 + tid;   // [0, 262144)
    const int lo = gid & 15;
    const int ktb = (gid >> 4) & 31;
    const int q4 = (gid >> 9) & 255;
    const int b = gid >> 17;
    const int* mrow = mask + ((int64_t)b << 20) + (int64_t)q4 * 4096 + ktb * 32 + lo;
    union { unsigned short us[8]; short8 v; } o;
    #pragma unroll
    for (int r = 0; r < 4; r++) {
      o.us[r * 2]     = mrow[r * 1024]      ? 0x3F80 : 0;
      o.us[r * 2 + 1] = mrow[r * 1024 + 16] ? 0x3F80 : 0;
    }
    ((short8*)Mf)[gid] = o.v;
  } else {
    const int row = id - 11264;                 // [0, 2048)
    const float4 v = ((const float4*)(x + (int64_t)row * D_MODEL))[tid];
    float s = v.x + v.y + v.z + v.w;
    float ss = v.x * v.x + v.y * v.y + v.z * v.z + v.w * v.w;
    #pragma unroll
    for (int m = 32; m; m >>= 1) {
      s += __shfl_down(s, m);
      ss += __shfl_down(ss, m);
    }
    const int wave = tid >> 6;
    if ((tid & 63) == 0) { red[wave] = s; red[4 + wave] = ss; }
    __syncthreads();
    if (tid == 0) {
      float S = red[0] + red[1] + red[2] + red[3];
      float SS = red[4] + red[5] + red[6] + red[7];
      float mean = S * (1.f / 1024.f);
      float var = (SS - 1024.f * mean * mean) * (1.f / 1023.f);
      float inv = 1.f / (sqrtf(fmaxf(var, 0.f)) + 1e-6f);
      red[8] = mean; red[9] = inv;
    }
    __syncthreads();
    const float mean = red[8], inv = red[9];
    const float4 a = ((const float4*)ln1a)[tid];
    const float4 bb = ((const float4*)ln1b)[tid];
    union { unsigned short us[4]; uint2 u2; } pk;
    pk.us[0] = f2bf(a.x * (v.x - mean) * inv + bb.x);
    pk.us[1] = f2bf(a.y * (v.y - mean) * inv + bb.y);
    pk.us[2] = f2bf(a.z * (v.z - mean) * inv + bb.z);
    pk.us[3] = f2bf(a.w * (v.w - mean) * inv + bb.w);
    ((uint2*)(n1 + (int64_t)row * D_MODEL))[tid] = pk.u2;
  }
}

// ---------------- LayerNorm (standalone, for LN2) -----------------------------
__global__ __launch_bounds__(256)
void ln_kernel(const float* __restrict__ x,
               const float* __restrict__ alpha,
               const float* __restrict__ beta,
               unsigned short* __restrict__ out) {
  const int row = blockIdx.x;
  const int tid = threadIdx.x;
  const float4 v = ((const float4*)(x + (int64_t)row * D_MODEL))[tid];
  float s = v.x + v.y + v.z + v.w;
  float ss = v.x * v.x + v.y * v.y + v.z * v.z + v.w * v.w;
  #pragma unroll
  for (int m = 32; m; m >>= 1) {
    s += __shfl_down(s, m);
    ss += __shfl_down(ss, m);
  }
  __shared__ float red[10];
  const int wave = tid >> 6;
  if ((tid & 63) == 0) { red[wave] = s; red[4 + wave] = ss; }
  __syncthreads();
  if (tid == 0) {
    float S = red[0] + red[1] + red[2] + red[3];
    float SS = red[4] + red[5] + red[6] + red[7];
    float mean = S * (1.f / 1024.f);
    float var = (SS - 1024.f * mean * mean) * (1.f / 1023.f);
    float inv = 1.f / (sqrtf(fmaxf(var, 0.f)) + 1e-6f);
    red[8] = mean; red[9] = inv;
  }
  __syncthreads();
  const float mean = red[8], inv = red[9];
  const float4 a = ((const float4*)alpha)[tid];
  const float4 bb = ((const float4*)beta)[tid];
  union { unsigned short us[4]; uint2 u2; } pk;
  pk.us[0] = f2bf(a.x * (v.x - mean) * inv + bb.x);
  pk.us[1] = f2bf(a.y * (v.y - mean) * inv + bb.y);
  pk.us[2] = f2bf(a.z * (v.z - mean) * inv + bb.z);
  pk.us[3] = f2bf(a.w * (v.w - mean) * inv + bb.w);
  ((uint2*)(out + (int64_t)row * D_MODEL))[tid] = pk.u2;
}

// ---------------- per-head transpose: qkv[b][s][h*64+d] -> qkvT[b][h][d][s] --
__global__ __launch_bounds__(256)
void qkvt_kernel(const unsigned short* __restrict__ qkv,
                 unsigned short* __restrict__ qkvT) {
  __shared__ unsigned short tile[32][33];
  const int s0 = blockIdx.x * 32, d0 = blockIdx.y * 32, bh = blockIdx.z;
  const int b = bh >> 4, h = bh & 15;
  const int tx = threadIdx.x & 31, ty = threadIdx.x >> 5;
  #pragma unroll
  for (int i = 0; i < 4; i++) {
    int r = ty + i * 8;
    tile[r][tx] = qkv[(int64_t)(b * S_LEN + s0 + r) * D_MODEL + h * DK + d0 + tx];
  }
  __syncthreads();
  #pragma unroll
  for (int i = 0; i < 4; i++) {
    int r = ty + i * 8;
    qkvT[(int64_t)(bh * DK + d0 + r) * S_LEN + s0 + tx] = tile[tx][r];
  }
}

// ---------------- GEMM (round-6 structure): C = A * Bt^T (+bias,+relu,+res) --
template<int BM, int BN, int BK, int BIAS, int RELU, int RES, int OUTBF, int KSPLIT>
__global__ __launch_bounds__(256)
void gemm_t(const unsigned short* __restrict__ A,
            const unsigned short* __restrict__ Bt,
            const float* __restrict__ bias,
            const float* __restrict__ res,
            void* __restrict__ outp,
            void* __restrict__ outp2,
            int M, int N, int K) {
  constexpr int NCH = BK / 8;
  constexpr int RPW = 512 / BK;
  constexpr int RPR = 2048 / BK;
  constexpr int RA = (BM * BK) / 2048;
  constexpr int RB = (BN * BK) / 2048;
  constexpr int MI = BM / 32;
  constexpr int NJ = BN / 32;
  constexpr int KK = BK / 32;

  __shared__ __align__(16) unsigned short As[BM * BK];
  __shared__ __align__(16) unsigned short Bs[BN * BK];

  const int tid = threadIdx.x;
  const int lane = tid & 63;
  const int wave = tid >> 6;
  const int lo = lane & 15, hi = lane >> 4;

  int bid = blockIdx.x;
  int split = 0;
  if (KSPLIT == 2) { split = bid & 1; bid >>= 1; }
  const int cpx = (gridDim.x / KSPLIT) >> 3;
  const int sid = (bid & 7) * cpx + (bid >> 3);
  const int nbx = N / BN;
  const int n0 = (sid % nbx) * BN;
  const int m0 = (sid / nbx) * BM;
  const int wr = (wave >> 1) * (BM / 2);
  const int wc = (wave & 1) * (BN / 2);

  auto swz = [](int row, int c) -> int {
    if (BK == 128) return c ^ ((row & 7) << 1);
    if (BK == 64)  return c ^ (row & 7);
    return c ^ ((row >> 1) & 3);   // BK == 32
  };

  const int sr = lane / NCH;
  const int sc = lane % NCH;

  f32x4 acc[MI][NJ] = {};

  const int kbeg = split * (K / KSPLIT);
  const int kend = kbeg + K / KSPLIT;
  for (int k0 = kbeg; k0 < kend; k0 += BK) {
    #pragma unroll
    for (int r = 0; r < RA; r++) {
      const int row = r * RPR + wave * RPW + sr;
      gll16(A + (int64_t)(m0 + row) * K + k0 + swz(row, sc) * 8,
            &As[r * 2048 + wave * 512]);
    }
    #pragma unroll
    for (int r = 0; r < RB; r++) {
      const int row = r * RPR + wave * RPW + sr;
      gll16(Bt + (int64_t)(n0 + row) * K + k0 + swz(row, sc) * 8,
            &Bs[r * 2048 + wave * 512]);
    }
    __syncthreads();
    #pragma unroll
    for (int kk = 0; kk < KK; kk++) {
      short8 af[MI], bfr[NJ];
      #pragma unroll
      for (int t = 0; t < MI; t++) {
        const int row = wr + t * 16 + lo;
        af[t] = *(const short8*)&As[row * BK + swz(row, kk * 4 + hi) * 8];
      }
      #pragma unroll
      for (int t = 0; t < NJ; t++) {
        const int row = wc + t * 16 + lo;
        bfr[t] = *(const short8*)&Bs[row * BK + swz(row, kk * 4 + hi) * 8];
      }
      #pragma unroll
      for (int i = 0; i < MI; i++)
        #pragma unroll
        for (int j = 0; j < NJ; j++)
          acc[i][j] = __builtin_amdgcn_mfma_f32_16x16x32_bf16(af[i], bfr[j], acc[i][j], 0, 0, 0);
    }
    __syncthreads();
  }

  float* Pout = (KSPLIT == 2) ? (split ? (float*)outp2 : (float*)outp) : nullptr;
  #pragma unroll
  for (int i = 0; i < MI; i++) {
    const int row = m0 + wr + i * 16 + hi * 4;
    #pragma unroll
    for (int j = 0; j < NJ; j++) {
      const int col = n0 + wc + j * 16 + lo;
      #pragma unroll
      for (int r = 0; r < 4; r++) {
        float v = acc[i][j][r];
        if (KSPLIT == 2) {
          Pout[(int64_t)(row + r) * N + col] = v;
        } else {
          if (BIAS) v += bias[col];
          if (RELU) v = fmaxf(v, 0.f);
          if (RES)  v += res[(int64_t)(row + r) * N + col];
          if (OUTBF)
            ((unsigned short*)outp)[(int64_t)(row + r) * N + col] = f2bf(v);
          else
            ((float*)outp)[(int64_t)(row + r) * N + col] = v;
        }
      }
    }
  }
}

// ---------------- FFN2 combine: out = x1(out) + B2 + P0 + P1 -----------------
__global__ __launch_bounds__(256)
void fcomb_kernel(const float* __restrict__ P0, const float* __restrict__ P1,
                  const float* __restrict__ bias, float* __restrict__ out) {
  const int i4 = blockIdx.x * 256 + threadIdx.x;     // 524288 float4
  const float4 a = ((const float4*)P0)[i4];
  const float4 b = ((const float4*)P1)[i4];
  const float4 bb = ((const float4*)bias)[i4 & 255];
  float4 c = ((const float4*)out)[i4];
  c.x += a.x + b.x + bb.x;
  c.y += a.y + b.y + bb.y;
  c.z += a.z + b.z + bb.z;
  c.w += a.w + b.w + bb.w;
  ((float4*)out)[i4] = c;
}

// -------- fused attention: LDS-staged K/V/M tiles, KV-split x2, XCD-local ----
__global__ __launch_bounds__(256)
void attn_kernel(const unsigned short* __restrict__ qkv,
                 const unsigned short* __restrict__ qkvT,
                 const unsigned short* __restrict__ Mf,
                 float* __restrict__ part,
                 float* __restrict__ psum) {
  __shared__ __align__(16) unsigned short Ks[64 * 64];
  __shared__ __align__(16) unsigned short Vs[64 * 64];
  __shared__ __align__(16) unsigned short Ms[512 * 8];
  __shared__ __align__(16) unsigned short Plds[4][16 * 40];
  const int tid = threadIdx.x;
  const int lane = tid & 63;
  const int wave = tid >> 6;
  const int lo = lane & 15, hi = lane >> 4;
  const int L = blockIdx.x;            // 1024 blocks
  const int xcd = L & 7, idx = L >> 3; // idx in [0,128)
  const int b = xcd >> 2;
  const int h = (xcd & 3) * 4 + (idx >> 5);
  const int split = (idx >> 4) & 1;
  const int qt = idx & 15;
  const int bh = b * 16 + h;
  const int q0 = qt * 64 + wave * 16;

  const unsigned short* qb =
      qkv + (int64_t)(b * S_LEN + q0 + lo) * D_MODEL + h * DK + hi * 8;
  const short8 qf0 = *(const short8*)qb;
  const short8 qf1 = *(const short8*)(qb + 32);

  f32x4 oacc[4] = {};
  float rsum[4] = {0.f, 0.f, 0.f, 0.f};
  unsigned short* Pw = Plds[wave];
  const int kbeg = split * 512;
  const int q4w = wave * 4 + hi;
  const int xr = lo & 7;

  for (int kti = 0; kti < 8; kti++) {
    const int kt = kbeg + kti * 64;
    #pragma unroll
    for (int r = 0; r < 2; r++) {
      const int c = r * 256 + tid;
      const int row = c >> 3;
      const int chg = (c & 7) ^ (row & 7);
      gll16(qkv + (int64_t)(b * S_LEN + kt + row) * D_MODEL + h * DK + chg * 8,
            &Ks[(r * 256 + wave * 64) * 8]);
      gll16(qkvT + (int64_t)(bh * DK + row) * S_LEN + kt + chg * 8,
            &Vs[(r * 256 + wave * 64) * 8]);
      const int q4l = c >> 5;
      const int u2 = (c >> 4) & 1;
      const int log = (c & 15) ^ q4l;
      gll16(Mf + ((int64_t)((b * 256 + qt * 16 + q4l) * 32 + (kt >> 5) + u2) * 16 + log) * 8,
            &Ms[(r * 256 + wave * 64) * 8]);
    }
    __syncthreads();
    #pragma unroll
    for (int u = 0; u < 2; u++) {
      const short8 kf00 = *(const short8*)&Ks[((u * 32 + lo) * 8 + (hi ^ xr)) * 8];
      const short8 kf01 = *(const short8*)&Ks[((u * 32 + lo) * 8 + ((4 + hi) ^ xr)) * 8];
      const short8 kf10 = *(const short8*)&Ks[((u * 32 + 16 + lo) * 8 + (hi ^ xr)) * 8];
      const short8 kf11 = *(const short8*)&Ks[((u * 32 + 16 + lo) * 8 + ((4 + hi) ^ xr)) * 8];
      const short8 mf = *(const short8*)&Ms[(q4w * 32 + u * 16 + (lo ^ q4w)) * 8];
      f32x4 s0 = {}, s1 = {};
      s0 = __builtin_amdgcn_mfma_f32_16x16x32_bf16(qf0, kf00, s0, 0, 0, 0);
      s0 = __builtin_amdgcn_mfma_f32_16x16x32_bf16(qf1, kf01, s0, 0, 0, 0);
      s1 = __builtin_amdgcn_mfma_f32_16x16x32_bf16(qf0, kf10, s1, 0, 0, 0);
      s1 = __builtin_amdgcn_mfma_f32_16x16x32_bf16(qf1, kf11, s1, 0, 0, 0);
      #pragma unroll
      for (int r = 0; r < 4; r++) {
        const float m0_ = bf2f((unsigned short)mf[r * 2]);
        const float m1_ = bf2f((unsigned short)mf[r * 2 + 1]);
        const float e0_ = __expf(s0[r] * 0.125f);
        const float e1_ = __expf(s1[r] * 0.125f);
        const float p0_ = fmaf(m0_, e0_ - 1.f, 1.f);
        const float p1_ = fmaf(m1_, e1_ - 1.f, 1.f);
        rsum[r] += p0_ + p1_;
        Pw[(hi * 4 + r) * 40 + lo]      = f2bf(p0_);
        Pw[(hi * 4 + r) * 40 + 16 + lo] = f2bf(p1_);
      }
      const short8 pf = *(const short8*)&Pw[lo * 40 + hi * 8];
      #pragma unroll
      for (int t = 0; t < 4; t++) {
        const short8 vf = *(const short8*)&Vs[((t * 16 + lo) * 8 + ((u * 4 + hi) ^ xr)) * 8];
        oacc[t] = __builtin_amdgcn_mfma_f32_16x16x32_bf16(pf, vf, oacc[t], 0, 0, 0);
      }
    }
    __syncthreads();
  }

  #pragma unroll
  for (int m = 1; m < 16; m <<= 1)
    #pragma unroll
    for (int r = 0; r < 4; r++) rsum[r] += __shfl_xor(rsum[r], m);

  const int64_t prow = (int64_t)(split * 32 + bh) * 1024;
  #pragma unroll
  for (int t = 0; t < 4; t++)
    #pragma unroll
    for (int r = 0; r < 4; r++)
      part[(prow + q0 + hi * 4 + r) * 64 + t * 16 + lo] = oacc[t][r];
  if (lo == 0)
    #pragma unroll
    for (int r = 0; r < 4; r++)
      psum[prow + q0 + hi * 4 + r] = rsum[r];
}

// ---------------- combine KV-split partials -> ctx (bf16) --------------------
__global__ __launch_bounds__(256)
void acomb_kernel(const float* __restrict__ part,
                  const float* __restrict__ psum,
                  unsigned short* __restrict__ ctx) {
  const int idx4 = blockIdx.x * 256 + threadIdx.x;   // 524288
  const int d4 = idx4 & 15;
  const int q = (idx4 >> 4) & 1023;
  const int bh = idx4 >> 14;
  const int b = bh >> 4, h = bh & 15;
  const float4* p4 = (const float4*)part;
  const float4 a0 = p4[(int64_t)(bh * 1024 + q) * 16 + d4];
  const float4 a1 = p4[524288 + (int64_t)(bh * 1024 + q) * 16 + d4];
  const float rs = psum[bh * 1024 + q] + psum[32768 + bh * 1024 + q];
  const float inv = 1.f / rs;
  union { unsigned short us[4]; uint2 u2; } pk;
  pk.us[0] = f2bf((a0.x + a1.x) * inv);
  pk.us[1] = f2bf((a0.y + a1.y) * inv);
  pk.us[2] = f2bf((a0.z + a1.z) * inv);
  pk.us[3] = f2bf((a0.w + a1.w) * inv);
  *(uint2*)(ctx + (int64_t)(b * S_LEN + q) * D_MODEL + h * DK + d4 * 4) = pk.u2;
}

// -----------------------------------------------------------------------------
extern "C" void kernel_launch(void* const* d_in, const int* in_sizes, int n_in,
                              void* d_out, int out_size, void* d_ws, size_t ws_size,
                              hipStream_t stream) {
  (void)in_sizes; (void)n_in; (void)out_size; (void)ws_size;
  const float* x    = (const float*)d_in[0];
  const int*   mask = (const int*)d_in[1];
  const float* Wq   = (const float*)d_in[2];
  const float* Wo   = (const float*)d_in[3];
  const float* W1   = (const float*)d_in[4];
  const float* B1   = (const float*)d_in[5];
  const float* W2   = (const float*)d_in[6];
  const float* B2   = (const float*)d_in[7];
  const float* ln1a = (const float*)d_in[8];
  const float* ln1b = (const float*)d_in[9];
  const float* ln2a = (const float*)d_in[10];
  const float* ln2b = (const float*)d_in[11];
  float* out = (float*)d_out;

  char* ws = (char*)d_ws;
  unsigned short* WqT  = (unsigned short*)(ws);                     // [0,2) MB
  unsigned short* WoT  = (unsigned short*)(ws + (2ull  << 20));     // [2,4)
  unsigned short* W1T  = (unsigned short*)(ws + (4ull  << 20));     // [4,12)
  float*          Pf0  = (float*)(ws + (4ull  << 20));              // FFN2 partial 0 (W1T dead)
  unsigned short* W2T  = (unsigned short*)(ws + (12ull << 20));     // [12,20)
  unsigned short* n1   = (unsigned short*)(ws + (20ull << 20));     // [20,24)
  float*          psum = (float*)(ws + (20ull << 20));              // reuses n1 (attn+)
  unsigned short* qkv  = (unsigned short*)(ws + (24ull << 20));     // [24,28)
  unsigned short* qkvT = (unsigned short*)(ws + (28ull << 20));     // [28,32)
  unsigned short* Mf   = (unsigned short*)(ws + (32ull << 20));     // [32,36)
  unsigned short* ctx  = (unsigned short*)(ws + (32ull << 20));     // [32,36) (Mf dead)
  float*          Pf1  = (float*)(ws + (32ull << 20));              // FFN2 partial 1 (ctx+n2 dead)
  unsigned short* n2   = (unsigned short*)(ws + (36ull << 20));     // [36,40)
  float*          part = (float*)(ws + (40ull << 20));              // [40,56) attn partials
  unsigned short* h1   = (unsigned short*)(ws + (40ull << 20));     // [40,56) FFN1 out (part dead)
  float* x1 = out;  // residual-1 result lives in d_out (fully rewritten later)

  dim3 blk(256);
  // prep: 10240 wt + 1024 mprep + 2048 ln1
  prep_kernel<<<13312, blk, 0, stream>>>(Wq, Wo, W1, W2, x, ln1a, ln1b, mask,
                                         WqT, WoT, W1T, W2T, Mf, n1);
  gemm_t<64,64,128, 0,0,0,1,1><<<512, blk, 0, stream>>>(n1, WqT, nullptr, nullptr, qkv, nullptr, 2048, 1024, 1024);
  qkvt_kernel<<<dim3(32, 2, 32), blk, 0, stream>>>(qkv, qkvT);
  attn_kernel<<<1024, blk, 0, stream>>>(qkv, qkvT, Mf, part, psum);
  acomb_kernel<<<2048, blk, 0, stream>>>(part, psum, ctx);
  gemm_t<64,64,128, 0,0,1,0,1><<<512, blk, 0, stream>>>(ctx, WoT, nullptr, x, x1, nullptr, 2048, 1024, 1024);
  ln_kernel<<<2048, blk, 0, stream>>>(x1, ln2a, ln2b, n2);
  // FFN1: 64x128 tile (r12 config, proven equal-best)
  gemm_t<64,128,64, 1,1,0,1,1><<<1024, blk, 0, stream>>>(n2, W1T, B1, nullptr, h1, nullptr, 2048, 4096, 1024);
  // FFN2: block K-split x2 -> f32 partials
  gemm_t<64,64,128, 0,0,0,0,2><<<1024, blk, 0, stream>>>(h1, W2T, nullptr, nullptr, Pf0, Pf1, 2048, 1024, 4096);
  fcomb_kernel<<<2048, blk, 0, stream>>>(Pf0, Pf1, B2, out);
}

// Round 15
// 134.177 us; speedup vs baseline: 3.8622x; 1.0151x over previous
//
#include <hip/hip_runtime.h>
#include <hip/hip_bf16.h>
#include <stdint.h>

#define D_MODEL 1024
#define S_LEN 1024
#define BATCH 2
#define NHEADS 16
#define DK 64
#define DFF 4096

typedef __attribute__((ext_vector_type(8))) short short8;
typedef __attribute__((ext_vector_type(4))) float f32x4;

__device__ __forceinline__ unsigned short f2bf(float f) {
  union { float f; unsigned u; } v; v.f = f;
  unsigned r = v.u + 0x7FFFu + ((v.u >> 16) & 1u);
  return (unsigned short)(r >> 16);
}

__device__ __forceinline__ float bf2f(unsigned short s) {
  union { float f; unsigned u; } v; v.u = ((unsigned)s) << 16;
  return v.f;
}

__device__ __forceinline__ void gll16(const void* g, void* l) {
  __builtin_amdgcn_global_load_lds(
      (const __attribute__((address_space(1))) void*)g,
      (__attribute__((address_space(3))) void*)l, 16, 0, 0);
}

// ======== prep: all 4 weight transposes + mask prep + LN1 in ONE launch ======
__global__ __launch_bounds__(256)
void prep_kernel(const float* __restrict__ Wq, const float* __restrict__ Wo,
                 const float* __restrict__ W1, const float* __restrict__ W2,
                 const float* __restrict__ x, const float* __restrict__ ln1a,
                 const float* __restrict__ ln1b, const int* __restrict__ mask,
                 unsigned short* __restrict__ WqT, unsigned short* __restrict__ WoT,
                 unsigned short* __restrict__ W1T, unsigned short* __restrict__ W2T,
                 unsigned short* __restrict__ Mf, unsigned short* __restrict__ n1) {
  __shared__ unsigned short tile[32][33];
  __shared__ float red[10];
  const int id = blockIdx.x;
  const int tid = threadIdx.x;
  if (id < 10240) {
    int wid = id;
    const float* W; unsigned short* Wt; int K, N, bx, by;
    if (wid < 1024)      { W = Wq; Wt = WqT; K = 1024; N = 1024; bx = wid & 31;  by = wid >> 5; }
    else if (wid < 2048) { wid -= 1024; W = Wo; Wt = WoT; K = 1024; N = 1024; bx = wid & 31;  by = wid >> 5; }
    else if (wid < 6144) { wid -= 2048; W = W1; Wt = W1T; K = 1024; N = 4096; bx = wid & 127; by = wid >> 7; }
    else                 { wid -= 6144; W = W2; Wt = W2T; K = 4096; N = 1024; bx = wid & 31;  by = wid >> 5; }
    const int k0 = by * 32, n0 = bx * 32;
    const int tx = tid & 31, ty = tid >> 5;
    #pragma unroll
    for (int i = 0; i < 4; i++) {
      int r = ty + i * 8;
      tile[r][tx] = f2bf(W[(int64_t)(k0 + r) * N + n0 + tx]);
    }
    __syncthreads();
    #pragma unroll
    for (int i = 0; i < 4; i++) {
      int r = ty + i * 8;
      Wt[(int64_t)(n0 + r) * K + k0 + tx] = tile[tx][r];
    }
  } else if (id < 11264) {
    const int gid = (id - 10240) * 256 + tid;   // [0, 262144)
    const int lo = gid & 15;
    const int ktb = (gid >> 4) & 31;
    const int q4 = (gid >> 9) & 255;
    const int b = gid >> 17;
    const int* mrow = mask + ((int64_t)b << 20) + (int64_t)q4 * 4096 + ktb * 32 + lo;
    union { unsigned short us[8]; short8 v; } o;
    #pragma unroll
    for (int r = 0; r < 4; r++) {
      o.us[r * 2]     = mrow[r * 1024]      ? 0x3F80 : 0;
      o.us[r * 2 + 1] = mrow[r * 1024 + 16] ? 0x3F80 : 0;
    }
    ((short8*)Mf)[gid] = o.v;
  } else {
    const int row = id - 11264;                 // [0, 2048)
    const float4 v = ((const float4*)(x + (int64_t)row * D_MODEL))[tid];
    float s = v.x + v.y + v.z + v.w;
    float ss = v.x * v.x + v.y * v.y + v.z * v.z + v.w * v.w;
    #pragma unroll
    for (int m = 32; m; m >>= 1) {
      s += __shfl_down(s, m);
      ss += __shfl_down(ss, m);
    }
    const int wave = tid >> 6;
    if ((tid & 63) == 0) { red[wave] = s; red[4 + wave] = ss; }
    __syncthreads();
    if (tid == 0) {
      float S = red[0] + red[1] + red[2] + red[3];
      float SS = red[4] + red[5] + red[6] + red[7];
      float mean = S * (1.f / 1024.f);
      float var = (SS - 1024.f * mean * mean) * (1.f / 1023.f);
      float inv = 1.f / (sqrtf(fmaxf(var, 0.f)) + 1e-6f);
      red[8] = mean; red[9] = inv;
    }
    __syncthreads();
    const float mean = red[8], inv = red[9];
    const float4 a = ((const float4*)ln1a)[tid];
    const float4 bb = ((const float4*)ln1b)[tid];
    union { unsigned short us[4]; uint2 u2; } pk;
    pk.us[0] = f2bf(a.x * (v.x - mean) * inv + bb.x);
    pk.us[1] = f2bf(a.y * (v.y - mean) * inv + bb.y);
    pk.us[2] = f2bf(a.z * (v.z - mean) * inv + bb.z);
    pk.us[3] = f2bf(a.w * (v.w - mean) * inv + bb.w);
    ((uint2*)(n1 + (int64_t)row * D_MODEL))[tid] = pk.u2;
  }
}

// ---------------- LayerNorm (standalone, for LN2) -----------------------------
__global__ __launch_bounds__(256)
void ln_kernel(const float* __restrict__ x,
               const float* __restrict__ alpha,
               const float* __restrict__ beta,
               unsigned short* __restrict__ out) {
  const int row = blockIdx.x;
  const int tid = threadIdx.x;
  const float4 v = ((const float4*)(x + (int64_t)row * D_MODEL))[tid];
  float s = v.x + v.y + v.z + v.w;
  float ss = v.x * v.x + v.y * v.y + v.z * v.z + v.w * v.w;
  #pragma unroll
  for (int m = 32; m; m >>= 1) {
    s += __shfl_down(s, m);
    ss += __shfl_down(ss, m);
  }
  __shared__ float red[10];
  const int wave = tid >> 6;
  if ((tid & 63) == 0) { red[wave] = s; red[4 + wave] = ss; }
  __syncthreads();
  if (tid == 0) {
    float S = red[0] + red[1] + red[2] + red[3];
    float SS = red[4] + red[5] + red[6] + red[7];
    float mean = S * (1.f / 1024.f);
    float var = (SS - 1024.f * mean * mean) * (1.f / 1023.f);
    float inv = 1.f / (sqrtf(fmaxf(var, 0.f)) + 1e-6f);
    red[8] = mean; red[9] = inv;
  }
  __syncthreads();
  const float mean = red[8], inv = red[9];
  const float4 a = ((const float4*)alpha)[tid];
  const float4 bb = ((const float4*)beta)[tid];
  union { unsigned short us[4]; uint2 u2; } pk;
  pk.us[0] = f2bf(a.x * (v.x - mean) * inv + bb.x);
  pk.us[1] = f2bf(a.y * (v.y - mean) * inv + bb.y);
  pk.us[2] = f2bf(a.z * (v.z - mean) * inv + bb.z);
  pk.us[3] = f2bf(a.w * (v.w - mean) * inv + bb.w);
  ((uint2*)(out + (int64_t)row * D_MODEL))[tid] = pk.u2;
}

// ---------------- per-head transpose: qkv[b][s][h*64+d] -> qkvT[b][h][d][s] --
__global__ __launch_bounds__(256)
void qkvt_kernel(const unsigned short* __restrict__ qkv,
                 unsigned short* __restrict__ qkvT) {
  __shared__ unsigned short tile[32][33];
  const int s0 = blockIdx.x * 32, d0 = blockIdx.y * 32, bh = blockIdx.z;
  const int b = bh >> 4, h = bh & 15;
  const int tx = threadIdx.x & 31, ty = threadIdx.x >> 5;
  #pragma unroll
  for (int i = 0; i < 4; i++) {
    int r = ty + i * 8;
    tile[r][tx] = qkv[(int64_t)(b * S_LEN + s0 + r) * D_MODEL + h * DK + d0 + tx];
  }
  __syncthreads();
  #pragma unroll
  for (int i = 0; i < 4; i++) {
    int r = ty + i * 8;
    qkvT[(int64_t)(bh * DK + d0 + r) * S_LEN + s0 + tx] = tile[tx][r];
  }
}

// ---------------- GEMM (round-6 structure): C = A * Bt^T (+bias,+relu,+res) --
// KSPLIT=2: partials written as bf16 when OUTBF=1, else f32.
template<int BM, int BN, int BK, int BIAS, int RELU, int RES, int OUTBF, int KSPLIT>
__global__ __launch_bounds__(256)
void gemm_t(const unsigned short* __restrict__ A,
            const unsigned short* __restrict__ Bt,
            const float* __restrict__ bias,
            const float* __restrict__ res,
            void* __restrict__ outp,
            void* __restrict__ outp2,
            int M, int N, int K) {
  constexpr int NCH = BK / 8;
  constexpr int RPW = 512 / BK;
  constexpr int RPR = 2048 / BK;
  constexpr int RA = (BM * BK) / 2048;
  constexpr int RB = (BN * BK) / 2048;
  constexpr int MI = BM / 32;
  constexpr int NJ = BN / 32;
  constexpr int KK = BK / 32;

  __shared__ __align__(16) unsigned short As[BM * BK];
  __shared__ __align__(16) unsigned short Bs[BN * BK];

  const int tid = threadIdx.x;
  const int lane = tid & 63;
  const int wave = tid >> 6;
  const int lo = lane & 15, hi = lane >> 4;

  int bid = blockIdx.x;
  int split = 0;
  if (KSPLIT == 2) { split = bid & 1; bid >>= 1; }
  const int cpx = (gridDim.x / KSPLIT) >> 3;
  const int sid = (bid & 7) * cpx + (bid >> 3);
  const int nbx = N / BN;
  const int n0 = (sid % nbx) * BN;
  const int m0 = (sid / nbx) * BM;
  const int wr = (wave >> 1) * (BM / 2);
  const int wc = (wave & 1) * (BN / 2);

  auto swz = [](int row, int c) -> int {
    if (BK == 128) return c ^ ((row & 7) << 1);
    if (BK == 64)  return c ^ (row & 7);
    return c ^ ((row >> 1) & 3);   // BK == 32
  };

  const int sr = lane / NCH;
  const int sc = lane % NCH;

  f32x4 acc[MI][NJ] = {};

  const int kbeg = split * (K / KSPLIT);
  const int kend = kbeg + K / KSPLIT;
  for (int k0 = kbeg; k0 < kend; k0 += BK) {
    #pragma unroll
    for (int r = 0; r < RA; r++) {
      const int row = r * RPR + wave * RPW + sr;
      gll16(A + (int64_t)(m0 + row) * K + k0 + swz(row, sc) * 8,
            &As[r * 2048 + wave * 512]);
    }
    #pragma unroll
    for (int r = 0; r < RB; r++) {
      const int row = r * RPR + wave * RPW + sr;
      gll16(Bt + (int64_t)(n0 + row) * K + k0 + swz(row, sc) * 8,
            &Bs[r * 2048 + wave * 512]);
    }
    __syncthreads();
    #pragma unroll
    for (int kk = 0; kk < KK; kk++) {
      short8 af[MI], bfr[NJ];
      #pragma unroll
      for (int t = 0; t < MI; t++) {
        const int row = wr + t * 16 + lo;
        af[t] = *(const short8*)&As[row * BK + swz(row, kk * 4 + hi) * 8];
      }
      #pragma unroll
      for (int t = 0; t < NJ; t++) {
        const int row = wc + t * 16 + lo;
        bfr[t] = *(const short8*)&Bs[row * BK + swz(row, kk * 4 + hi) * 8];
      }
      #pragma unroll
      for (int i = 0; i < MI; i++)
        #pragma unroll
        for (int j = 0; j < NJ; j++)
          acc[i][j] = __builtin_amdgcn_mfma_f32_16x16x32_bf16(af[i], bfr[j], acc[i][j], 0, 0, 0);
    }
    __syncthreads();
  }

  void* PoutV = (KSPLIT == 2) ? (split ? outp2 : outp) : nullptr;
  #pragma unroll
  for (int i = 0; i < MI; i++) {
    const int row = m0 + wr + i * 16 + hi * 4;
    #pragma unroll
    for (int j = 0; j < NJ; j++) {
      const int col = n0 + wc + j * 16 + lo;
      #pragma unroll
      for (int r = 0; r < 4; r++) {
        float v = acc[i][j][r];
        if (KSPLIT == 2) {
          if (OUTBF)
            ((unsigned short*)PoutV)[(int64_t)(row + r) * N + col] = f2bf(v);
          else
            ((float*)PoutV)[(int64_t)(row + r) * N + col] = v;
        } else {
          if (BIAS) v += bias[col];
          if (RELU) v = fmaxf(v, 0.f);
          if (RES)  v += res[(int64_t)(row + r) * N + col];
          if (OUTBF)
            ((unsigned short*)outp)[(int64_t)(row + r) * N + col] = f2bf(v);
          else
            ((float*)outp)[(int64_t)(row + r) * N + col] = v;
        }
      }
    }
  }
}

// ---------------- FFN2 combine: out = x1(out) + B2 + P0 + P1 (bf16 parts) ----
__global__ __launch_bounds__(256)
void fcomb_kernel(const unsigned short* __restrict__ P0,
                  const unsigned short* __restrict__ P1,
                  const float* __restrict__ bias, float* __restrict__ out) {
  const int i4 = blockIdx.x * 256 + threadIdx.x;     // 524288 groups of 4
  const uint2 a2 = ((const uint2*)P0)[i4];
  const uint2 b2 = ((const uint2*)P1)[i4];
  const float4 bb = ((const float4*)bias)[i4 & 255];
  float4 c = ((const float4*)out)[i4];
  c.x += bf2f((unsigned short)(a2.x & 0xFFFF)) + bf2f((unsigned short)(b2.x & 0xFFFF)) + bb.x;
  c.y += bf2f((unsigned short)(a2.x >> 16))    + bf2f((unsigned short)(b2.x >> 16))    + bb.y;
  c.z += bf2f((unsigned short)(a2.y & 0xFFFF)) + bf2f((unsigned short)(b2.y & 0xFFFF)) + bb.z;
  c.w += bf2f((unsigned short)(a2.y >> 16))    + bf2f((unsigned short)(b2.y >> 16))    + bb.w;
  ((float4*)out)[i4] = c;
}

// -------- fused attention: LDS-staged K/V/M tiles, KV-split x2, XCD-local ----
// part is bf16 (unnormalized O partials); psum stays f32.
__global__ __launch_bounds__(256)
void attn_kernel(const unsigned short* __restrict__ qkv,
                 const unsigned short* __restrict__ qkvT,
                 const unsigned short* __restrict__ Mf,
                 unsigned short* __restrict__ part,
                 float* __restrict__ psum) {
  __shared__ __align__(16) unsigned short Ks[64 * 64];
  __shared__ __align__(16) unsigned short Vs[64 * 64];
  __shared__ __align__(16) unsigned short Ms[512 * 8];
  __shared__ __align__(16) unsigned short Plds[4][16 * 40];
  const int tid = threadIdx.x;
  const int lane = tid & 63;
  const int wave = tid >> 6;
  const int lo = lane & 15, hi = lane >> 4;
  const int L = blockIdx.x;            // 1024 blocks
  const int xcd = L & 7, idx = L >> 3; // idx in [0,128)
  const int b = xcd >> 2;
  const int h = (xcd & 3) * 4 + (idx >> 5);
  const int split = (idx >> 4) & 1;
  const int qt = idx & 15;
  const int bh = b * 16 + h;
  const int q0 = qt * 64 + wave * 16;

  const unsigned short* qb =
      qkv + (int64_t)(b * S_LEN + q0 + lo) * D_MODEL + h * DK + hi * 8;
  const short8 qf0 = *(const short8*)qb;
  const short8 qf1 = *(const short8*)(qb + 32);

  f32x4 oacc[4] = {};
  float rsum[4] = {0.f, 0.f, 0.f, 0.f};
  unsigned short* Pw = Plds[wave];
  const int kbeg = split * 512;
  const int q4w = wave * 4 + hi;
  const int xr = lo & 7;

  for (int kti = 0; kti < 8; kti++) {
    const int kt = kbeg + kti * 64;
    #pragma unroll
    for (int r = 0; r < 2; r++) {
      const int c = r * 256 + tid;
      const int row = c >> 3;
      const int chg = (c & 7) ^ (row & 7);
      gll16(qkv + (int64_t)(b * S_LEN + kt + row) * D_MODEL + h * DK + chg * 8,
            &Ks[(r * 256 + wave * 64) * 8]);
      gll16(qkvT + (int64_t)(bh * DK + row) * S_LEN + kt + chg * 8,
            &Vs[(r * 256 + wave * 64) * 8]);
      const int q4l = c >> 5;
      const int u2 = (c >> 4) & 1;
      const int log = (c & 15) ^ q4l;
      gll16(Mf + ((int64_t)((b * 256 + qt * 16 + q4l) * 32 + (kt >> 5) + u2) * 16 + log) * 8,
            &Ms[(r * 256 + wave * 64) * 8]);
    }
    __syncthreads();
    #pragma unroll
    for (int u = 0; u < 2; u++) {
      const short8 kf00 = *(const short8*)&Ks[((u * 32 + lo) * 8 + (hi ^ xr)) * 8];
      const short8 kf01 = *(const short8*)&Ks[((u * 32 + lo) * 8 + ((4 + hi) ^ xr)) * 8];
      const short8 kf10 = *(const short8*)&Ks[((u * 32 + 16 + lo) * 8 + (hi ^ xr)) * 8];
      const short8 kf11 = *(const short8*)&Ks[((u * 32 + 16 + lo) * 8 + ((4 + hi) ^ xr)) * 8];
      const short8 mf = *(const short8*)&Ms[(q4w * 32 + u * 16 + (lo ^ q4w)) * 8];
      f32x4 s0 = {}, s1 = {};
      s0 = __builtin_amdgcn_mfma_f32_16x16x32_bf16(qf0, kf00, s0, 0, 0, 0);
      s0 = __builtin_amdgcn_mfma_f32_16x16x32_bf16(qf1, kf01, s0, 0, 0, 0);
      s1 = __builtin_amdgcn_mfma_f32_16x16x32_bf16(qf0, kf10, s1, 0, 0, 0);
      s1 = __builtin_amdgcn_mfma_f32_16x16x32_bf16(qf1, kf11, s1, 0, 0, 0);
      #pragma unroll
      for (int r = 0; r < 4; r++) {
        const float m0_ = bf2f((unsigned short)mf[r * 2]);
        const float m1_ = bf2f((unsigned short)mf[r * 2 + 1]);
        const float e0_ = __expf(s0[r] * 0.125f);
        const float e1_ = __expf(s1[r] * 0.125f);
        const float p0_ = fmaf(m0_, e0_ - 1.f, 1.f);
        const float p1_ = fmaf(m1_, e1_ - 1.f, 1.f);
        rsum[r] += p0_ + p1_;
        Pw[(hi * 4 + r) * 40 + lo]      = f2bf(p0_);
        Pw[(hi * 4 + r) * 40 + 16 + lo] = f2bf(p1_);
      }
      const short8 pf = *(const short8*)&Pw[lo * 40 + hi * 8];
      #pragma unroll
      for (int t = 0; t < 4; t++) {
        const short8 vf = *(const short8*)&Vs[((t * 16 + lo) * 8 + ((u * 4 + hi) ^ xr)) * 8];
        oacc[t] = __builtin_amdgcn_mfma_f32_16x16x32_bf16(pf, vf, oacc[t], 0, 0, 0);
      }
    }
    __syncthreads();
  }

  #pragma unroll
  for (int m = 1; m < 16; m <<= 1)
    #pragma unroll
    for (int r = 0; r < 4; r++) rsum[r] += __shfl_xor(rsum[r], m);

  const int64_t prow = (int64_t)(split * 32 + bh) * 1024;
  #pragma unroll
  for (int t = 0; t < 4; t++)
    #pragma unroll
    for (int r = 0; r < 4; r++)
      part[(prow + q0 + hi * 4 + r) * 64 + t * 16 + lo] = f2bf(oacc[t][r]);
  if (lo == 0)
    #pragma unroll
    for (int r = 0; r < 4; r++)
      psum[prow + q0 + hi * 4 + r] = rsum[r];
}

// ---------------- combine KV-split partials (bf16) -> ctx (bf16) -------------
__global__ __launch_bounds__(256)
void acomb_kernel(const unsigned short* __restrict__ part,
                  const float* __restrict__ psum,
                  unsigned short* __restrict__ ctx) {
  const int idx4 = blockIdx.x * 256 + threadIdx.x;   // 524288
  const int d4 = idx4 & 15;
  const int q = (idx4 >> 4) & 1023;
  const int bh = idx4 >> 14;
  const int b = bh >> 4, h = bh & 15;
  const uint2* p2 = (const uint2*)part;              // 4 bf16 per uint2
  const uint2 a0 = p2[(int64_t)(bh * 1024 + q) * 16 + d4];
  const uint2 a1 = p2[524288 + (int64_t)(bh * 1024 + q) * 16 + d4];
  const float rs = psum[bh * 1024 + q] + psum[32768 + bh * 1024 + q];
  const float inv = 1.f / rs;
  union { unsigned short us[4]; uint2 u2; } pk;
  pk.us[0] = f2bf((bf2f((unsigned short)(a0.x & 0xFFFF)) + bf2f((unsigned short)(a1.x & 0xFFFF))) * inv);
  pk.us[1] = f2bf((bf2f((unsigned short)(a0.x >> 16))    + bf2f((unsigned short)(a1.x >> 16)))    * inv);
  pk.us[2] = f2bf((bf2f((unsigned short)(a0.y & 0xFFFF)) + bf2f((unsigned short)(a1.y & 0xFFFF))) * inv);
  pk.us[3] = f2bf((bf2f((unsigned short)(a0.y >> 16))    + bf2f((unsigned short)(a1.y >> 16)))    * inv);
  *(uint2*)(ctx + (int64_t)(b * S_LEN + q) * D_MODEL + h * DK + d4 * 4) = pk.u2;
}

// -----------------------------------------------------------------------------
extern "C" void kernel_launch(void* const* d_in, const int* in_sizes, int n_in,
                              void* d_out, int out_size, void* d_ws, size_t ws_size,
                              hipStream_t stream) {
  (void)in_sizes; (void)n_in; (void)out_size; (void)ws_size;
  const float* x    = (const float*)d_in[0];
  const int*   mask = (const int*)d_in[1];
  const float* Wq   = (const float*)d_in[2];
  const float* Wo   = (const float*)d_in[3];
  const float* W1   = (const float*)d_in[4];
  const float* B1   = (const float*)d_in[5];
  const float* W2   = (const float*)d_in[6];
  const float* B2   = (const float*)d_in[7];
  const float* ln1a = (const float*)d_in[8];
  const float* ln1b = (const float*)d_in[9];
  const float* ln2a = (const float*)d_in[10];
  const float* ln2b = (const float*)d_in[11];
  float* out = (float*)d_out;

  char* ws = (char*)d_ws;
  unsigned short* WqT  = (unsigned short*)(ws);                     // [0,2) MB
  unsigned short* WoT  = (unsigned short*)(ws + (2ull  << 20));     // [2,4)
  unsigned short* W1T  = (unsigned short*)(ws + (4ull  << 20));     // [4,12)
  unsigned short* Pf0  = (unsigned short*)(ws + (4ull  << 20));     // FFN2 bf16 partial 0 (W1T dead)
  unsigned short* W2T  = (unsigned short*)(ws + (12ull << 20));     // [12,20)
  unsigned short* n1   = (unsigned short*)(ws + (20ull << 20));     // [20,24)
  float*          psum = (float*)(ws + (20ull << 20));              // reuses n1 (attn+)
  unsigned short* qkv  = (unsigned short*)(ws + (24ull << 20));     // [24,28)
  unsigned short* qkvT = (unsigned short*)(ws + (28ull << 20));     // [28,32)
  unsigned short* Mf   = (unsigned short*)(ws + (32ull << 20));     // [32,36)
  unsigned short* ctx  = (unsigned short*)(ws + (32ull << 20));     // [32,36) (Mf dead)
  unsigned short* Pf1  = (unsigned short*)(ws + (36ull << 20));     // FFN2 bf16 partial 1 (n2 dead)
  unsigned short* n2   = (unsigned short*)(ws + (36ull << 20));     // [36,40)
  unsigned short* part = (unsigned short*)(ws + (40ull << 20));     // [40,48) attn bf16 partials
  unsigned short* h1   = (unsigned short*)(ws + (40ull << 20));     // [40,56) FFN1 out (part dead)
  float* x1 = out;  // residual-1 result lives in d_out (fully rewritten later)

  dim3 blk(256);
  // prep: 10240 wt + 1024 mprep + 2048 ln1
  prep_kernel<<<13312, blk, 0, stream>>>(Wq, Wo, W1, W2, x, ln1a, ln1b, mask,
                                         WqT, WoT, W1T, W2T, Mf, n1);
  gemm_t<64,64,128, 0,0,0,1,1><<<512, blk, 0, stream>>>(n1, WqT, nullptr, nullptr, qkv, nullptr, 2048, 1024, 1024);
  qkvt_kernel<<<dim3(32, 2, 32), blk, 0, stream>>>(qkv, qkvT);
  attn_kernel<<<1024, blk, 0, stream>>>(qkv, qkvT, Mf, part, psum);
  acomb_kernel<<<2048, blk, 0, stream>>>(part, psum, ctx);
  gemm_t<64,64,128, 0,0,1,0,1><<<512, blk, 0, stream>>>(ctx, WoT, nullptr, x, x1, nullptr, 2048, 1024, 1024);
  ln_kernel<<<2048, blk, 0, stream>>>(x1, ln2a, ln2b, n2);
  // FFN1: 64x128 tile (proven equal-best). NOTE: n2 aliases Pf1 region but
  // FFN1 consumes n2 BEFORE FFN2 writes Pf1 — ordering is safe.
  gemm_t<64,128,64, 1,1,0,1,1><<<1024, blk, 0, stream>>>(n2, W1T, B1, nullptr, h1, nullptr, 2048, 4096, 1024);
  // FFN2: block K-split x2 -> bf16 partials
  gemm_t<64,64,128, 0,0,0,1,2><<<1024, blk, 0, stream>>>(h1, W2T, nullptr, nullptr, Pf0, Pf1, 2048, 1024, 4096);
  fcomb_kernel<<<2048, blk, 0, stream>>>(Pf0, Pf1, B2, out);
}

// Round 16
// 131.338 us; speedup vs baseline: 3.9457x; 1.0216x over previous
//
#include <hip/hip_runtime.h>
#include <hip/hip_bf16.h>
#include <stdint.h>

#define D_MODEL 1024
#define S_LEN 1024
#define BATCH 2
#define NHEADS 16
#define DK 64
#define DFF 4096

typedef __attribute__((ext_vector_type(8))) short short8;
typedef __attribute__((ext_vector_type(4))) float f32x4;

__device__ __forceinline__ unsigned short f2bf(float f) {
  union { float f; unsigned u; } v; v.f = f;
  unsigned r = v.u + 0x7FFFu + ((v.u >> 16) & 1u);
  return (unsigned short)(r >> 16);
}

__device__ __forceinline__ float bf2f(unsigned short s) {
  union { float f; unsigned u; } v; v.u = ((unsigned)s) << 16;
  return v.f;
}

__device__ __forceinline__ void gll16(const void* g, void* l) {
  __builtin_amdgcn_global_load_lds(
      (const __attribute__((address_space(1))) void*)g,
      (__attribute__((address_space(3))) void*)l, 16, 0, 0);
}

// ======== prep: all 4 weight transposes + mask prep + LN1 in ONE launch ======
__global__ __launch_bounds__(256)
void prep_kernel(const float* __restrict__ Wq, const float* __restrict__ Wo,
                 const float* __restrict__ W1, const float* __restrict__ W2,
                 const float* __restrict__ x, const float* __restrict__ ln1a,
                 const float* __restrict__ ln1b, const int* __restrict__ mask,
                 unsigned short* __restrict__ WqT, unsigned short* __restrict__ WoT,
                 unsigned short* __restrict__ W1T, unsigned short* __restrict__ W2T,
                 unsigned short* __restrict__ Mf, unsigned short* __restrict__ n1) {
  __shared__ unsigned short tile[32][33];
  __shared__ float red[10];
  const int id = blockIdx.x;
  const int tid = threadIdx.x;
  if (id < 10240) {
    int wid = id;
    const float* W; unsigned short* Wt; int K, N, bx, by;
    if (wid < 1024)      { W = Wq; Wt = WqT; K = 1024; N = 1024; bx = wid & 31;  by = wid >> 5; }
    else if (wid < 2048) { wid -= 1024; W = Wo; Wt = WoT; K = 1024; N = 1024; bx = wid & 31;  by = wid >> 5; }
    else if (wid < 6144) { wid -= 2048; W = W1; Wt = W1T; K = 1024; N = 4096; bx = wid & 127; by = wid >> 7; }
    else                 { wid -= 6144; W = W2; Wt = W2T; K = 4096; N = 1024; bx = wid & 31;  by = wid >> 5; }
    const int k0 = by * 32, n0 = bx * 32;
    const int tx = tid & 31, ty = tid >> 5;
    #pragma unroll
    for (int i = 0; i < 4; i++) {
      int r = ty + i * 8;
      tile[r][tx] = f2bf(W[(int64_t)(k0 + r) * N + n0 + tx]);
    }
    __syncthreads();
    #pragma unroll
    for (int i = 0; i < 4; i++) {
      int r = ty + i * 8;
      Wt[(int64_t)(n0 + r) * K + k0 + tx] = tile[tx][r];
    }
  } else if (id < 11264) {
    const int gid = (id - 10240) * 256 + tid;   // [0, 262144)
    const int lo = gid & 15;
    const int ktb = (gid >> 4) & 31;
    const int q4 = (gid >> 9) & 255;
    const int b = gid >> 17;
    const int* mrow = mask + ((int64_t)b << 20) + (int64_t)q4 * 4096 + ktb * 32 + lo;
    union { unsigned short us[8]; short8 v; } o;
    #pragma unroll
    for (int r = 0; r < 4; r++) {
      o.us[r * 2]     = mrow[r * 1024]      ? 0x3F80 : 0;
      o.us[r * 2 + 1] = mrow[r * 1024 + 16] ? 0x3F80 : 0;
    }
    ((short8*)Mf)[gid] = o.v;
  } else {
    const int row = id - 11264;                 // [0, 2048)
    const float4 v = ((const float4*)(x + (int64_t)row * D_MODEL))[tid];
    float s = v.x + v.y + v.z + v.w;
    float ss = v.x * v.x + v.y * v.y + v.z * v.z + v.w * v.w;
    #pragma unroll
    for (int m = 32; m; m >>= 1) {
      s += __shfl_down(s, m);
      ss += __shfl_down(ss, m);
    }
    const int wave = tid >> 6;
    if ((tid & 63) == 0) { red[wave] = s; red[4 + wave] = ss; }
    __syncthreads();
    if (tid == 0) {
      float S = red[0] + red[1] + red[2] + red[3];
      float SS = red[4] + red[5] + red[6] + red[7];
      float mean = S * (1.f / 1024.f);
      float var = (SS - 1024.f * mean * mean) * (1.f / 1023.f);
      float inv = 1.f / (sqrtf(fmaxf(var, 0.f)) + 1e-6f);
      red[8] = mean; red[9] = inv;
    }
    __syncthreads();
    const float mean = red[8], inv = red[9];
    const float4 a = ((const float4*)ln1a)[tid];
    const float4 bb = ((const float4*)ln1b)[tid];
    union { unsigned short us[4]; uint2 u2; } pk;
    pk.us[0] = f2bf(a.x * (v.x - mean) * inv + bb.x);
    pk.us[1] = f2bf(a.y * (v.y - mean) * inv + bb.y);
    pk.us[2] = f2bf(a.z * (v.z - mean) * inv + bb.z);
    pk.us[3] = f2bf(a.w * (v.w - mean) * inv + bb.w);
    ((uint2*)(n1 + (int64_t)row * D_MODEL))[tid] = pk.u2;
  }
}

// ---------------- LayerNorm (standalone, for LN2) -----------------------------
__global__ __launch_bounds__(256)
void ln_kernel(const float* __restrict__ x,
               const float* __restrict__ alpha,
               const float* __restrict__ beta,
               unsigned short* __restrict__ out) {
  const int row = blockIdx.x;
  const int tid = threadIdx.x;
  const float4 v = ((const float4*)(x + (int64_t)row * D_MODEL))[tid];
  float s = v.x + v.y + v.z + v.w;
  float ss = v.x * v.x + v.y * v.y + v.z * v.z + v.w * v.w;
  #pragma unroll
  for (int m = 32; m; m >>= 1) {
    s += __shfl_down(s, m);
    ss += __shfl_down(ss, m);
  }
  __shared__ float red[10];
  const int wave = tid >> 6;
  if ((tid & 63) == 0) { red[wave] = s; red[4 + wave] = ss; }
  __syncthreads();
  if (tid == 0) {
    float S = red[0] + red[1] + red[2] + red[3];
    float SS = red[4] + red[5] + red[6] + red[7];
    float mean = S * (1.f / 1024.f);
    float var = (SS - 1024.f * mean * mean) * (1.f / 1023.f);
    float inv = 1.f / (sqrtf(fmaxf(var, 0.f)) + 1e-6f);
    red[8] = mean; red[9] = inv;
  }
  __syncthreads();
  const float mean = red[8], inv = red[9];
  const float4 a = ((const float4*)alpha)[tid];
  const float4 bb = ((const float4*)beta)[tid];
  union { unsigned short us[4]; uint2 u2; } pk;
  pk.us[0] = f2bf(a.x * (v.x - mean) * inv + bb.x);
  pk.us[1] = f2bf(a.y * (v.y - mean) * inv + bb.y);
  pk.us[2] = f2bf(a.z * (v.z - mean) * inv + bb.z);
  pk.us[3] = f2bf(a.w * (v.w - mean) * inv + bb.w);
  ((uint2*)(out + (int64_t)row * D_MODEL))[tid] = pk.u2;
}

// ---------------- GEMM (round-6 structure): C = A * Bt^T (+bias,+relu,+res) --
// KSPLIT=2: partials written bf16 (OUTBF=1) or f32. QKVT=1 (Wq GEMM only):
// epilogue also writes the per-head transpose to outp2 (qkvT) via LDS tile —
// valid because BN=64=DK means each block's n-range is exactly one head.
template<int BM, int BN, int BK, int BIAS, int RELU, int RES, int OUTBF, int KSPLIT, int QKVT>
__global__ __launch_bounds__(256)
void gemm_t(const unsigned short* __restrict__ A,
            const unsigned short* __restrict__ Bt,
            const float* __restrict__ bias,
            const float* __restrict__ res,
            void* __restrict__ outp,
            void* __restrict__ outp2,
            int M, int N, int K) {
  constexpr int NCH = BK / 8;
  constexpr int RPW = 512 / BK;
  constexpr int RPR = 2048 / BK;
  constexpr int RA = (BM * BK) / 2048;
  constexpr int RB = (BN * BK) / 2048;
  constexpr int MI = BM / 32;
  constexpr int NJ = BN / 32;
  constexpr int KK = BK / 32;

  __shared__ __align__(16) unsigned short As[BM * BK];
  __shared__ __align__(16) unsigned short Bs[BN * BK];

  const int tid = threadIdx.x;
  const int lane = tid & 63;
  const int wave = tid >> 6;
  const int lo = lane & 15, hi = lane >> 4;

  int bid = blockIdx.x;
  int split = 0;
  if (KSPLIT == 2) { split = bid & 1; bid >>= 1; }
  const int cpx = (gridDim.x / KSPLIT) >> 3;
  const int sid = (bid & 7) * cpx + (bid >> 3);
  const int nbx = N / BN;
  const int n0 = (sid % nbx) * BN;
  const int m0 = (sid / nbx) * BM;
  const int wr = (wave >> 1) * (BM / 2);
  const int wc = (wave & 1) * (BN / 2);

  auto swz = [](int row, int c) -> int {
    if (BK == 128) return c ^ ((row & 7) << 1);
    if (BK == 64)  return c ^ (row & 7);
    return c ^ ((row >> 1) & 3);   // BK == 32
  };

  const int sr = lane / NCH;
  const int sc = lane % NCH;

  f32x4 acc[MI][NJ] = {};

  const int kbeg = split * (K / KSPLIT);
  const int kend = kbeg + K / KSPLIT;
  for (int k0 = kbeg; k0 < kend; k0 += BK) {
    #pragma unroll
    for (int r = 0; r < RA; r++) {
      const int row = r * RPR + wave * RPW + sr;
      gll16(A + (int64_t)(m0 + row) * K + k0 + swz(row, sc) * 8,
            &As[r * 2048 + wave * 512]);
    }
    #pragma unroll
    for (int r = 0; r < RB; r++) {
      const int row = r * RPR + wave * RPW + sr;
      gll16(Bt + (int64_t)(n0 + row) * K + k0 + swz(row, sc) * 8,
            &Bs[r * 2048 + wave * 512]);
    }
    __syncthreads();
    #pragma unroll
    for (int kk = 0; kk < KK; kk++) {
      short8 af[MI], bfr[NJ];
      #pragma unroll
      for (int t = 0; t < MI; t++) {
        const int row = wr + t * 16 + lo;
        af[t] = *(const short8*)&As[row * BK + swz(row, kk * 4 + hi) * 8];
      }
      #pragma unroll
      for (int t = 0; t < NJ; t++) {
        const int row = wc + t * 16 + lo;
        bfr[t] = *(const short8*)&Bs[row * BK + swz(row, kk * 4 + hi) * 8];
      }
      #pragma unroll
      for (int i = 0; i < MI; i++)
        #pragma unroll
        for (int j = 0; j < NJ; j++)
          acc[i][j] = __builtin_amdgcn_mfma_f32_16x16x32_bf16(af[i], bfr[j], acc[i][j], 0, 0, 0);
    }
    __syncthreads();
  }

  void* PoutV = (KSPLIT == 2) ? (split ? outp2 : outp) : nullptr;
  unsigned short* Tl = As;   // free after final loop barrier; 64*68 shorts used
  #pragma unroll
  for (int i = 0; i < MI; i++) {
    const int row = m0 + wr + i * 16 + hi * 4;
    #pragma unroll
    for (int j = 0; j < NJ; j++) {
      const int col = n0 + wc + j * 16 + lo;
      #pragma unroll
      for (int r = 0; r < 4; r++) {
        float v = acc[i][j][r];
        if (KSPLIT == 2) {
          if (OUTBF)
            ((unsigned short*)PoutV)[(int64_t)(row + r) * N + col] = f2bf(v);
          else
            ((float*)PoutV)[(int64_t)(row + r) * N + col] = v;
        } else {
          if (BIAS) v += bias[col];
          if (RELU) v = fmaxf(v, 0.f);
          if (RES)  v += res[(int64_t)(row + r) * N + col];
          if (OUTBF) {
            const unsigned short bv = f2bf(v);
            ((unsigned short*)outp)[(int64_t)(row + r) * N + col] = bv;
            if (QKVT)
              Tl[(wc + j * 16 + lo) * 68 + (wr + i * 16 + hi * 4 + r)] = bv;
          } else {
            ((float*)outp)[(int64_t)(row + r) * N + col] = v;
          }
        }
      }
    }
  }
  if (QKVT) {
    __syncthreads();
    const int h = n0 >> 6;          // BN=64=DK: block's n-range == one head
    const int b2 = m0 >> 10;
    const int sbase = m0 & 1023;
    unsigned short* qT = (unsigned short*)outp2;
    #pragma unroll
    for (int e = 0; e < 4; e++) {
      const int idx = e * 256 + tid;     // 1024 uint2 = 64 d x 16 s-quads
      const int d = idx >> 4;
      const int s4 = (idx & 15) * 4;
      union { unsigned short us[4]; uint2 u2; } pk;
      pk.us[0] = Tl[d * 68 + s4];
      pk.us[1] = Tl[d * 68 + s4 + 1];
      pk.us[2] = Tl[d * 68 + s4 + 2];
      pk.us[3] = Tl[d * 68 + s4 + 3];
      *(uint2*)&qT[(int64_t)((b2 * 16 + h) * 64 + d) * 1024 + sbase + s4] = pk.u2;
    }
  }
}

// ---------------- FFN2 combine: out = x1(out) + B2 + P0 + P1 (bf16 parts) ----
__global__ __launch_bounds__(256)
void fcomb_kernel(const unsigned short* __restrict__ P0,
                  const unsigned short* __restrict__ P1,
                  const float* __restrict__ bias, float* __restrict__ out) {
  const int i4 = blockIdx.x * 256 + threadIdx.x;     // 524288 groups of 4
  const uint2 a2 = ((const uint2*)P0)[i4];
  const uint2 b2 = ((const uint2*)P1)[i4];
  const float4 bb = ((const float4*)bias)[i4 & 255];
  float4 c = ((const float4*)out)[i4];
  c.x += bf2f((unsigned short)(a2.x & 0xFFFF)) + bf2f((unsigned short)(b2.x & 0xFFFF)) + bb.x;
  c.y += bf2f((unsigned short)(a2.x >> 16))    + bf2f((unsigned short)(b2.x >> 16))    + bb.y;
  c.z += bf2f((unsigned short)(a2.y & 0xFFFF)) + bf2f((unsigned short)(b2.y & 0xFFFF)) + bb.z;
  c.w += bf2f((unsigned short)(a2.y >> 16))    + bf2f((unsigned short)(b2.y >> 16))    + bb.w;
  ((float4*)out)[i4] = c;
}

// -------- fused attention: LDS-staged K/V/M tiles, KV-split x2, XCD-local ----
// part is bf16 (unnormalized O partials); psum stays f32.
__global__ __launch_bounds__(256)
void attn_kernel(const unsigned short* __restrict__ qkv,
                 const unsigned short* __restrict__ qkvT,
                 const unsigned short* __restrict__ Mf,
                 unsigned short* __restrict__ part,
                 float* __restrict__ psum) {
  __shared__ __align__(16) unsigned short Ks[64 * 64];
  __shared__ __align__(16) unsigned short Vs[64 * 64];
  __shared__ __align__(16) unsigned short Ms[512 * 8];
  __shared__ __align__(16) unsigned short Plds[4][16 * 40];
  const int tid = threadIdx.x;
  const int lane = tid & 63;
  const int wave = tid >> 6;
  const int lo = lane & 15, hi = lane >> 4;
  const int L = blockIdx.x;            // 1024 blocks
  const int xcd = L & 7, idx = L >> 3; // idx in [0,128)
  const int b = xcd >> 2;
  const int h = (xcd & 3) * 4 + (idx >> 5);
  const int split = (idx >> 4) & 1;
  const int qt = idx & 15;
  const int bh = b * 16 + h;
  const int q0 = qt * 64 + wave * 16;

  const unsigned short* qb =
      qkv + (int64_t)(b * S_LEN + q0 + lo) * D_MODEL + h * DK + hi * 8;
  const short8 qf0 = *(const short8*)qb;
  const short8 qf1 = *(const short8*)(qb + 32);

  f32x4 oacc[4] = {};
  float rsum[4] = {0.f, 0.f, 0.f, 0.f};
  unsigned short* Pw = Plds[wave];
  const int kbeg = split * 512;
  const int q4w = wave * 4 + hi;
  const int xr = lo & 7;

  for (int kti = 0; kti < 8; kti++) {
    const int kt = kbeg + kti * 64;
    #pragma unroll
    for (int r = 0; r < 2; r++) {
      const int c = r * 256 + tid;
      const int row = c >> 3;
      const int chg = (c & 7) ^ (row & 7);
      gll16(qkv + (int64_t)(b * S_LEN + kt + row) * D_MODEL + h * DK + chg * 8,
            &Ks[(r * 256 + wave * 64) * 8]);
      gll16(qkvT + (int64_t)(bh * DK + row) * S_LEN + kt + chg * 8,
            &Vs[(r * 256 + wave * 64) * 8]);
      const int q4l = c >> 5;
      const int u2 = (c >> 4) & 1;
      const int log = (c & 15) ^ q4l;
      gll16(Mf + ((int64_t)((b * 256 + qt * 16 + q4l) * 32 + (kt >> 5) + u2) * 16 + log) * 8,
            &Ms[(r * 256 + wave * 64) * 8]);
    }
    __syncthreads();
    #pragma unroll
    for (int u = 0; u < 2; u++) {
      const short8 kf00 = *(const short8*)&Ks[((u * 32 + lo) * 8 + (hi ^ xr)) * 8];
      const short8 kf01 = *(const short8*)&Ks[((u * 32 + lo) * 8 + ((4 + hi) ^ xr)) * 8];
      const short8 kf10 = *(const short8*)&Ks[((u * 32 + 16 + lo) * 8 + (hi ^ xr)) * 8];
      const short8 kf11 = *(const short8*)&Ks[((u * 32 + 16 + lo) * 8 + ((4 + hi) ^ xr)) * 8];
      const short8 mf = *(const short8*)&Ms[(q4w * 32 + u * 16 + (lo ^ q4w)) * 8];
      f32x4 s0 = {}, s1 = {};
      s0 = __builtin_amdgcn_mfma_f32_16x16x32_bf16(qf0, kf00, s0, 0, 0, 0);
      s0 = __builtin_amdgcn_mfma_f32_16x16x32_bf16(qf1, kf01, s0, 0, 0, 0);
      s1 = __builtin_amdgcn_mfma_f32_16x16x32_bf16(qf0, kf10, s1, 0, 0, 0);
      s1 = __builtin_amdgcn_mfma_f32_16x16x32_bf16(qf1, kf11, s1, 0, 0, 0);
      #pragma unroll
      for (int r = 0; r < 4; r++) {
        const float m0_ = bf2f((unsigned short)mf[r * 2]);
        const float m1_ = bf2f((unsigned short)mf[r * 2 + 1]);
        const float e0_ = __expf(s0[r] * 0.125f);
        const float e1_ = __expf(s1[r] * 0.125f);
        const float p0_ = fmaf(m0_, e0_ - 1.f, 1.f);
        const float p1_ = fmaf(m1_, e1_ - 1.f, 1.f);
        rsum[r] += p0_ + p1_;
        Pw[(hi * 4 + r) * 40 + lo]      = f2bf(p0_);
        Pw[(hi * 4 + r) * 40 + 16 + lo] = f2bf(p1_);
      }
      const short8 pf = *(const short8*)&Pw[lo * 40 + hi * 8];
      #pragma unroll
      for (int t = 0; t < 4; t++) {
        const short8 vf = *(const short8*)&Vs[((t * 16 + lo) * 8 + ((u * 4 + hi) ^ xr)) * 8];
        oacc[t] = __builtin_amdgcn_mfma_f32_16x16x32_bf16(pf, vf, oacc[t], 0, 0, 0);
      }
    }
    __syncthreads();
  }

  #pragma unroll
  for (int m = 1; m < 16; m <<= 1)
    #pragma unroll
    for (int r = 0; r < 4; r++) rsum[r] += __shfl_xor(rsum[r], m);

  const int64_t prow = (int64_t)(split * 32 + bh) * 1024;
  #pragma unroll
  for (int t = 0; t < 4; t++)
    #pragma unroll
    for (int r = 0; r < 4; r++)
      part[(prow + q0 + hi * 4 + r) * 64 + t * 16 + lo] = f2bf(oacc[t][r]);
  if (lo == 0)
    #pragma unroll
    for (int r = 0; r < 4; r++)
      psum[prow + q0 + hi * 4 + r] = rsum[r];
}

// ---------------- combine KV-split partials (bf16) -> ctx (bf16) -------------
__global__ __launch_bounds__(256)
void acomb_kernel(const unsigned short* __restrict__ part,
                  const float* __restrict__ psum,
                  unsigned short* __restrict__ ctx) {
  const int idx4 = blockIdx.x * 256 + threadIdx.x;   // 524288
  const int d4 = idx4 & 15;
  const int q = (idx4 >> 4) & 1023;
  const int bh = idx4 >> 14;
  const int b = bh >> 4, h = bh & 15;
  const uint2* p2 = (const uint2*)part;              // 4 bf16 per uint2
  const uint2 a0 = p2[(int64_t)(bh * 1024 + q) * 16 + d4];
  const uint2 a1 = p2[524288 + (int64_t)(bh * 1024 + q) * 16 + d4];
  const float rs = psum[bh * 1024 + q] + psum[32768 + bh * 1024 + q];
  const float inv = 1.f / rs;
  union { unsigned short us[4]; uint2 u2; } pk;
  pk.us[0] = f2bf((bf2f((unsigned short)(a0.x & 0xFFFF)) + bf2f((unsigned short)(a1.x & 0xFFFF))) * inv);
  pk.us[1] = f2bf((bf2f((unsigned short)(a0.x >> 16))    + bf2f((unsigned short)(a1.x >> 16)))    * inv);
  pk.us[2] = f2bf((bf2f((unsigned short)(a0.y & 0xFFFF)) + bf2f((unsigned short)(a1.y & 0xFFFF))) * inv);
  pk.us[3] = f2bf((bf2f((unsigned short)(a0.y >> 16))    + bf2f((unsigned short)(a1.y >> 16)))    * inv);
  *(uint2*)(ctx + (int64_t)(b * S_LEN + q) * D_MODEL + h * DK + d4 * 4) = pk.u2;
}

// -----------------------------------------------------------------------------
extern "C" void kernel_launch(void* const* d_in, const int* in_sizes, int n_in,
                              void* d_out, int out_size, void* d_ws, size_t ws_size,
                              hipStream_t stream) {
  (void)in_sizes; (void)n_in; (void)out_size; (void)ws_size;
  const float* x    = (const float*)d_in[0];
  const int*   mask = (const int*)d_in[1];
  const float* Wq   = (const float*)d_in[2];
  const float* Wo   = (const float*)d_in[3];
  const float* W1   = (const float*)d_in[4];
  const float* B1   = (const float*)d_in[5];
  const float* W2   = (const float*)d_in[6];
  const float* B2   = (const float*)d_in[7];
  const float* ln1a = (const float*)d_in[8];
  const float* ln1b = (const float*)d_in[9];
  const float* ln2a = (const float*)d_in[10];
  const float* ln2b = (const float*)d_in[11];
  float* out = (float*)d_out;

  char* ws = (char*)d_ws;
  unsigned short* WqT  = (unsigned short*)(ws);                     // [0,2) MB
  unsigned short* WoT  = (unsigned short*)(ws + (2ull  << 20));     // [2,4)
  unsigned short* W1T  = (unsigned short*)(ws + (4ull  << 20));     // [4,12)
  unsigned short* Pf0  = (unsigned short*)(ws + (4ull  << 20));     // FFN2 bf16 partial 0 (W1T dead)
  unsigned short* W2T  = (unsigned short*)(ws + (12ull << 20));     // [12,20)
  unsigned short* n1   = (unsigned short*)(ws + (20ull << 20));     // [20,24)
  float*          psum = (float*)(ws + (20ull << 20));              // reuses n1 (attn+)
  unsigned short* qkv  = (unsigned short*)(ws + (24ull << 20));     // [24,28)
  unsigned short* qkvT = (unsigned short*)(ws + (28ull << 20));     // [28,32)
  unsigned short* Mf   = (unsigned short*)(ws + (32ull << 20));     // [32,36)
  unsigned short* ctx  = (unsigned short*)(ws + (32ull << 20));     // [32,36) (Mf dead)
  unsigned short* Pf1  = (unsigned short*)(ws + (36ull << 20));     // FFN2 bf16 partial 1 (n2 dead)
  unsigned short* n2   = (unsigned short*)(ws + (36ull << 20));     // [36,40)
  unsigned short* part = (unsigned short*)(ws + (40ull << 20));     // [40,48) attn bf16 partials
  unsigned short* h1   = (unsigned short*)(ws + (40ull << 20));     // [40,56) FFN1 out (part dead)
  float* x1 = out;  // residual-1 result lives in d_out (fully rewritten later)

  dim3 blk(256);
  // prep: 10240 wt + 1024 mprep + 2048 ln1
  prep_kernel<<<13312, blk, 0, stream>>>(Wq, Wo, W1, W2, x, ln1a, ln1b, mask,
                                         WqT, WoT, W1T, W2T, Mf, n1);
  // Wq GEMM with fused qkv + qkvT (per-head transpose) epilogue
  gemm_t<64,64,128, 0,0,0,1,1,1><<<512, blk, 0, stream>>>(n1, WqT, nullptr, nullptr, qkv, qkvT, 2048, 1024, 1024);
  attn_kernel<<<1024, blk, 0, stream>>>(qkv, qkvT, Mf, part, psum);
  acomb_kernel<<<2048, blk, 0, stream>>>(part, psum, ctx);
  gemm_t<64,64,128, 0,0,1,0,1,0><<<512, blk, 0, stream>>>(ctx, WoT, nullptr, x, x1, nullptr, 2048, 1024, 1024);
  ln_kernel<<<2048, blk, 0, stream>>>(x1, ln2a, ln2b, n2);
  // FFN1: 64x128 tile (proven equal-best). n2 aliases Pf1 region but is
  // consumed before FFN2 writes Pf1 — ordering safe.
  gemm_t<64,128,64, 1,1,0,1,1,0><<<1024, blk, 0, stream>>>(n2, W1T, B1, nullptr, h1, nullptr, 2048, 4096, 1024);
  // FFN2: block K-split x2 -> bf16 partials
  gemm_t<64,64,128, 0,0,0,1,2,0><<<1024, blk, 0, stream>>>(h1, W2T, nullptr, nullptr, Pf0, Pf1, 2048, 1024, 4096);
  fcomb_kernel<<<2048, blk, 0, stream>>>(Pf0, Pf1, B2, out);
}